// Round 8
// baseline (504.539 us; speedup 1.0000x reference)
//
#include <hip/hip_runtime.h>

typedef unsigned short u16;
typedef unsigned int u32;
typedef __bf16 bf16x8 __attribute__((ext_vector_type(8)));
typedef __bf16 bf16x4 __attribute__((ext_vector_type(4)));
typedef u16 u16x8 __attribute__((ext_vector_type(8)));
typedef u32 u32x2 __attribute__((ext_vector_type(2)));
typedef u32 u32x4 __attribute__((ext_vector_type(4)));
typedef float f32x4 __attribute__((ext_vector_type(4)));

#define Ss 2048
#define Hh 16

#define WAITV(n) asm volatile("s_waitcnt vmcnt(" #n ")" ::: "memory")
#define BAR() __builtin_amdgcn_s_barrier()
#define SCHED0() __builtin_amdgcn_sched_barrier(0)

__device__ __forceinline__ void gll16(const void* g, void* l) {
  __builtin_amdgcn_global_load_lds((const __attribute__((address_space(1))) void*)g,
                                   (__attribute__((address_space(3))) void*)l, 16, 0, 0);
}

__device__ __forceinline__ bf16x8 lds8(const u16* base, int byteoff) {
  return __builtin_bit_cast(bf16x8, *(const u16x8*)((const char*)base + byteoff));
}
__device__ __forceinline__ bf16x8 g8(const u16* p) {
  return __builtin_bit_cast(bf16x8, *(const u16x8*)p);
}

// ---------------- K0a: convert Q/K/V embeddings f32 -> bf16 (8/thread) -----
__global__ __launch_bounds__(256) void convert_x(const float* __restrict__ xq,
                                                 const float* __restrict__ xk,
                                                 const float* __restrict__ xv,
                                                 u16* __restrict__ dst) {
  int z = blockIdx.y;
  const float* src = (z == 0) ? xq : ((z == 1) ? xk : xv);
  u16* d = dst + (size_t)z * (8192ull * 1024);
  size_t i = ((size_t)blockIdx.x * 256 + threadIdx.x) * 8;
  float4 v0 = *(const float4*)(src + i);
  float4 v1 = *(const float4*)(src + i + 4);
  bf16x8 o;
  o[0] = (__bf16)v0.x; o[1] = (__bf16)v0.y; o[2] = (__bf16)v0.z; o[3] = (__bf16)v0.w;
  o[4] = (__bf16)v1.x; o[5] = (__bf16)v1.y; o[6] = (__bf16)v1.z; o[7] = (__bf16)v1.w;
  *(bf16x8*)(d + i) = o;
}

// ---------------- K0b: transpose + convert weights: Wt[n][k] = W[k][n] -----
__global__ __launch_bounds__(256) void conv_w(const float* __restrict__ wq,
                                              const float* __restrict__ wk,
                                              const float* __restrict__ wv,
                                              const float* __restrict__ wo,
                                              u16* __restrict__ wt) {
  int z = blockIdx.z;
  const float* W = (z == 0) ? wq : (z == 1) ? wk : (z == 2) ? wv : wo;
  u16* O = wt + (size_t)z * (1024ull * 1024);
  __shared__ float tile[64][65];
  int tk = blockIdx.x * 64, tn = blockIdx.y * 64;
  int t = threadIdx.x;
#pragma unroll
  for (int p = 0; p < 4; ++p) {
    int idx = p * 256 + t;
    int r = idx >> 4, c4 = (idx & 15) << 2;
    float4 v = *(const float4*)(W + (size_t)(tk + r) * 1024 + tn + c4);
    tile[r][c4 + 0] = v.x; tile[r][c4 + 1] = v.y;
    tile[r][c4 + 2] = v.z; tile[r][c4 + 3] = v.w;
  }
  __syncthreads();
#pragma unroll
  for (int p = 0; p < 4; ++p) {
    int idx = p * 256 + t;
    int n = idx >> 4, k4 = (idx & 15) << 2;
    bf16x4 o;
    o[0] = (__bf16)tile[k4 + 0][n]; o[1] = (__bf16)tile[k4 + 1][n];
    o[2] = (__bf16)tile[k4 + 2][n]; o[3] = (__bf16)tile[k4 + 3][n];
    *(bf16x4*)(O + (size_t)(tn + n) * 1024 + tk + k4) = o;
  }
}

// ---------------- K0c: pack mask int32 -> bitmask (2/thread) ----------------
__global__ __launch_bounds__(256) void pack_mask(const int* __restrict__ m,
                                                 u32* __restrict__ bits) {
  size_t base = (size_t)blockIdx.x * 512;
  int t = threadIdx.x;
  int w = t >> 6, lane = t & 63;
  bool v0 = (m[base + t] != 0);
  bool v1 = (m[base + 256 + t] != 0);
  unsigned long long b0 = __ballot(v0);
  unsigned long long b1 = __ballot(v1);
  size_t wbase = (base >> 5) + (w << 1);
  if (lane == 0) {
    bits[wbase] = (u32)b0;
    bits[wbase + 8] = (u32)b1;
  } else if (lane == 32) {
    bits[wbase + 1] = (u32)(b0 >> 32);
    bits[wbase + 9] = (u32)(b1 >> 32);
  }
}

// ---------------- K1: QKV projection GEMM (counted-vmcnt + XCD swizzle) ----
// z=0 -> Q [bh][s][dk] scaled by (1/8)*log2(e), z=1 -> K [bh][s][dk],
// z=2 -> V transposed [bh][dv][s]
__global__ __launch_bounds__(256) void gemm_qkv(const u16* __restrict__ Xbf,
                                                const u16* __restrict__ Wt,
                                                const float* __restrict__ bq,
                                                const float* __restrict__ bk,
                                                const float* __restrict__ bv,
                                                u16* __restrict__ OutQK,
                                                u16* __restrict__ Vt) {
  int z = blockIdx.z;
  const u16* A = Xbf + (size_t)z * (8192ull * 1024);
  const u16* Bw = Wt + (size_t)z * (1024ull * 1024);
  const float* bias = (z == 0) ? bq : ((z == 1) ? bk : bv);
  u16* O = OutQK + (size_t)z * (8192ull * 1024);
  float scale = (z == 0) ? (0.125f * 1.4426950408889634f) : 1.0f;

  __shared__ __attribute__((aligned(16))) u16 Al[2][128 * 32];
  __shared__ __attribute__((aligned(16))) u16 Bl[2][128 * 32];

  int t = threadIdx.x, w = t >> 6, l = t & 63, lg = l >> 4, lr = l & 15;
  // XCD swizzle: all 8 N-tiles of one M-tile land on one XCD (dispatch n%8)
  int n_ = blockIdx.x;
  int cx = n_ & 7, slot = n_ >> 3;
  int m0 = (((slot >> 3) << 3) | cx) * 128;
  int n0 = (slot & 7) * 128;
  int wm = (w >> 1) * 64, wn = (w & 1) * 64;

  f32x4 acc[4][4] = {};

#define STAGE_AB(kt_, buf_)                                                    \
  {                                                                            \
    _Pragma("unroll") for (int i = 0; i < 2; ++i) {                            \
      int c = t + i * 256;                                                     \
      int d = c << 4;                                                          \
      int row = d >> 6, off = d & 63;                                          \
      int soff = off ^ ((row & 3) << 4);                                       \
      gll16(A + (size_t)(m0 + row) * 1024 + (kt_) + (soff >> 1),               \
            (char*)Al[buf_] + d);                                              \
      gll16(Bw + (size_t)(n0 + row) * 1024 + (kt_) + (soff >> 1),              \
            (char*)Bl[buf_] + d);                                              \
    }                                                                          \
  }

  STAGE_AB(0, 0);

  for (int tt = 0; tt < 32; ++tt) {
    int cur = tt & 1;
    if (tt < 31) {
      STAGE_AB((tt + 1) * 32, cur ^ 1);
      WAITV(4);
    } else {
      WAITV(0);
    }
    SCHED0();
    BAR();
    bf16x8 af[4], bfr[4];
#pragma unroll
    for (int mf = 0; mf < 4; ++mf) {
      int row = wm + mf * 16 + lr;
      af[mf] = lds8(Al[cur], (row << 6) + ((lg ^ (row & 3)) << 4));
    }
#pragma unroll
    for (int nf = 0; nf < 4; ++nf) {
      int row = wn + nf * 16 + lr;
      bfr[nf] = lds8(Bl[cur], (row << 6) + ((lg ^ (row & 3)) << 4));
    }
#pragma unroll
    for (int mf = 0; mf < 4; ++mf)
#pragma unroll
      for (int nf = 0; nf < 4; ++nf)
        acc[mf][nf] = __builtin_amdgcn_mfma_f32_16x16x32_bf16(af[mf], bfr[nf], acc[mf][nf], 0, 0, 0);
    BAR();
  }
#undef STAGE_AB

  if (z == 2) {
#pragma unroll
    for (int mf = 0; mf < 4; ++mf)
#pragma unroll
      for (int nf = 0; nf < 4; ++nf) {
        int m = m0 + wm + mf * 16 + lg * 4;
        int n = n0 + wn + nf * 16 + lr;
        bf16x4 ov;
#pragma unroll
        for (int r = 0; r < 4; ++r) ov[r] = (__bf16)(acc[mf][nf][r] + bias[n]);
        int b_ = m >> 11, s_ = m & 2047, hh = n >> 6, dd = n & 63;
        *(bf16x4*)(Vt + (((size_t)(b_ * 16 + hh)) * 64 + dd) * 2048 + s_) = ov;
      }
  } else {
#pragma unroll
    for (int mf = 0; mf < 4; ++mf)
#pragma unroll
      for (int nf = 0; nf < 4; ++nf)
#pragma unroll
        for (int r = 0; r < 4; ++r) {
          int m = m0 + wm + mf * 16 + lg * 4 + r;
          int n = n0 + wn + nf * 16 + lr;
          float v = (acc[mf][nf][r] + bias[n]) * scale;
          int b_ = m >> 11, s_ = m & 2047, hh = n >> 6, dd = n & 63;
          *(__bf16*)&O[(((size_t)(b_ * 16 + hh)) * 2048 + s_) * 64 + dd] = (__bf16)v;
        }
  }
}

// ---------------- K2: staged fused attention ----------------
// pass 0: KC=128 K-tiles (halved barrier count); pass 1: KC=64 (R7-proven)
__global__ __launch_bounds__(256, 4) void attn_kernel(const u16* __restrict__ Qs,
                                                      const u16* __restrict__ Ks,
                                                      const u16* __restrict__ Vt,
                                                      const u32* __restrict__ Mbits,
                                                      float* __restrict__ attn,
                                                      u16* __restrict__ Ctx) {
  int bid = blockIdx.x;  // 2048 blocks; one head's 32 q-blocks stay on one XCD
  int xcd = bid & 7, j = bid >> 3;
  int bh = xcd * 8 + (j >> 5);
  int q0 = (j & 31) * 64;
  int b = bh >> 4, h = bh & 15;
  int t = threadIdx.x;
  int w = t >> 6, l = t & 63, lg = l >> 4, lr = l & 15;

  const u16* Qb = Qs + (size_t)bh * (Ss * 64);
  const u16* Kb = Ks + (size_t)bh * (Ss * 64);
  const u16* Vb = Vt + (size_t)bh * (64 * Ss);
  int qrow = w * 16 + lr;
  const u32* Mrow = Mbits + ((size_t)b * Ss + q0 + qrow) * 64;

  // flat 40 KB arena:
  //  pass 0: K dbuf [2][16KB] @ 0
  //  pass 1: K dbuf [2][8KB] @ 0, V dbuf [2][8KB] @ 16K, P @ 32K
  __shared__ __attribute__((aligned(16))) char SMb[40960];
  u16* Pl = (u16*)(SMb + 32768);

  // staging geometry: thread t covers row srow (+32i), 16B col chunk, swizzled
  int srow = t >> 3;
  int skoff = (((t & 7) << 4) ^ ((srow & 7) << 4));

// pass-0 stage: 128-row K tile (16 KB), 4 issues
#define STAGE_K2(kc_, buf_)                                                    \
  {                                                                            \
    _Pragma("unroll") for (int i = 0; i < 4; ++i)                              \
        gll16(Kb + (size_t)((kc_) + srow + 32 * i) * 64 + (skoff >> 1),        \
              SMb + (buf_)*16384 + i * 4096 + (t << 4));                       \
  }
// pass-1 stage: 64-row tiles (8 KB), 2 issues each
#define STAGE_K(kc_, buf_)                                                     \
  {                                                                            \
    gll16(Kb + (size_t)((kc_) + srow) * 64 + (skoff >> 1),                     \
          SMb + (buf_)*8192 + (t << 4));                                       \
    gll16(Kb + (size_t)((kc_) + srow + 32) * 64 + (skoff >> 1),                \
          SMb + (buf_)*8192 + (t << 4) + 4096);                                \
  }
#define STAGE_V(kc_, buf_)                                                     \
  {                                                                            \
    gll16(Vb + (size_t)srow * 2048 + (kc_) + (skoff >> 1),                     \
          SMb + 16384 + (buf_)*8192 + (t << 4));                               \
    gll16(Vb + (size_t)(srow + 32) * 2048 + (kc_) + (skoff >> 1),              \
          SMb + 16384 + (buf_)*8192 + (t << 4) + 4096);                        \
  }

  bf16x8 qf[2];
  {
    const u16* qr = Qb + (size_t)(q0 + qrow) * 64;
    qf[0] = g8(qr + lg * 8);
    qf[1] = g8(qr + 32 + lg * 8);
  }

  float* arow = attn + ((size_t)bh * Ss + q0 + qrow) * Ss;
  int swzq = (lr & 7) << 4;

  // ================= pass 0: rowsums (KC=128) =================
  float rsum = 0.f;
  {
    STAGE_K2(0, 0);
    u32x4 mq = *(const u32x4*)(Mrow);
    u32x4 mqn;
    for (int tt = 0; tt < 16; ++tt) {
      int cur = tt & 1;
      if (tt < 15) {
        STAGE_K2((tt + 1) * 128, cur ^ 1);
        mqn = *(const u32x4*)(Mrow + ((tt + 1) << 2));
        WAITV(5);
      } else {
        WAITV(0);
      }
      SCHED0();
      BAR();
      const u16* Kc = (const u16*)(SMb + cur * 16384);
#pragma unroll
      for (int nf = 0; nf < 8; ++nf) {
        int krow = nf * 16 + lr;
        int base = krow << 7, swz = (krow & 7) << 4;
        f32x4 sc = {};
        __builtin_amdgcn_s_setprio(1);
        sc = __builtin_amdgcn_mfma_f32_16x16x32_bf16(
            lds8(Kc, base + ((lg << 4) ^ swz)), qf[0], sc, 0, 0, 0);
        sc = __builtin_amdgcn_mfma_f32_16x16x32_bf16(
            lds8(Kc, base + ((64 + (lg << 4)) ^ swz)), qf[1], sc, 0, 0, 0);
        __builtin_amdgcn_s_setprio(0);
        u32 mb = mq[nf >> 1] >> (((nf & 1) << 4) + (lg << 2));
#pragma unroll
        for (int r = 0; r < 4; ++r)
          rsum += ((mb >> r) & 1) ? 0.f : __builtin_amdgcn_exp2f(sc[r]);
      }
      mq = mqn;
      BAR();
    }
  }
  float inv;
  {
    float s = rsum;
    s += __shfl_xor(s, 16);
    s += __shfl_xor(s, 32);
    inv = 1.0f / s;
  }

  // ================= pass 1: write attention + P.V (KC=64, R7) ============
  f32x4 ctx[4] = {};
  {
    STAGE_K(0, 0);
    STAGE_V(0, 0);
    u32x2 mq = *(const u32x2*)(Mrow);
    u32x2 mqn;
    for (int tt = 0; tt < 32; ++tt) {
      int cur = tt & 1;
      if (tt == 0) {
        STAGE_K(64, 1);
        STAGE_V(64, 1);
        mqn = *(const u32x2*)(Mrow + 2);
        WAITV(5);
      } else if (tt < 31) {
        STAGE_K((tt + 1) * 64, cur ^ 1);
        STAGE_V((tt + 1) * 64, cur ^ 1);
        mqn = *(const u32x2*)(Mrow + ((tt + 1) << 1));
        WAITV(9);
      } else {
        WAITV(4);
      }
      SCHED0();
      BAR();
      const u16* Kc = (const u16*)(SMb + cur * 8192);
      const u16* Vc = (const u16*)(SMb + 16384 + cur * 8192);
      int kc = tt * 64;
#pragma unroll
      for (int nf = 0; nf < 4; ++nf) {
        int krow = nf * 16 + lr;
        int base = krow << 7, swz = (krow & 7) << 4;
        f32x4 sc = {};
        __builtin_amdgcn_s_setprio(1);
        sc = __builtin_amdgcn_mfma_f32_16x16x32_bf16(
            lds8(Kc, base + ((lg << 4) ^ swz)), qf[0], sc, 0, 0, 0);
        sc = __builtin_amdgcn_mfma_f32_16x16x32_bf16(
            lds8(Kc, base + ((64 + (lg << 4)) ^ swz)), qf[1], sc, 0, 0, 0);
        __builtin_amdgcn_s_setprio(0);
        u32 mb = mq[nf >> 1] >> (((nf & 1) << 4) + (lg << 2));
        f32x4 p4;
#pragma unroll
        for (int r = 0; r < 4; ++r)
          p4[r] = (((mb >> r) & 1) ? 0.f : __builtin_amdgcn_exp2f(sc[r])) * inv;
        __builtin_nontemporal_store(p4, (f32x4*)(arow + kc + nf * 16 + lg * 4));
        bf16x4 pb;
#pragma unroll
        for (int r = 0; r < 4; ++r) pb[r] = (__bf16)p4[r];
        *(bf16x4*)((char*)Pl + (qrow << 7) + (((nf << 5) + (lg << 3)) ^ swzq)) = pb;
      }
      // P.V over this 64-k tile
      __builtin_amdgcn_s_setprio(1);
#pragma unroll
      for (int ks = 0; ks < 2; ++ks) {
        bf16x8 pf = lds8(Pl, (qrow << 7) + (((ks << 6) + (lg << 4)) ^ swzq));
#pragma unroll
        for (int nfo = 0; nfo < 4; ++nfo) {
          int vr = nfo * 16 + lr;
          bf16x8 vf = lds8(Vc,
                           (vr << 7) + (((ks << 6) + (lg << 4)) ^ ((vr & 7) << 4)));
          ctx[nfo] = __builtin_amdgcn_mfma_f32_16x16x32_bf16(pf, vf, ctx[nfo], 0, 0, 0);
        }
      }
      __builtin_amdgcn_s_setprio(0);
      mq = mqn;
      BAR();
    }
  }
#undef STAGE_K2
#undef STAGE_K
#undef STAGE_V

  // write context: Ctx[b][s][h*64+dd]
#pragma unroll
  for (int nfo = 0; nfo < 4; ++nfo)
#pragma unroll
    for (int r = 0; r < 4; ++r) {
      int qr2 = w * 16 + lg * 4 + r;
      int dd = nfo * 16 + lr;
      *(__bf16*)&Ctx[((size_t)b * Ss + q0 + qr2) * (Hh * 64) + h * 64 + dd] =
          (__bf16)ctx[nfo][r];
    }
}

// ---------------- K3: output projection + bias + residual (XCD swizzle) ----
__global__ __launch_bounds__(256) void gemm_out(const u16* __restrict__ Ctx,
                                                const u16* __restrict__ Wot,
                                                const float* __restrict__ bo,
                                                const float* __restrict__ resid,
                                                float* __restrict__ preLN) {
  __shared__ __attribute__((aligned(16))) u16 Al[2][128 * 32];
  __shared__ __attribute__((aligned(16))) u16 Bl[2][128 * 32];

  int t = threadIdx.x, w = t >> 6, l = t & 63, lg = l >> 4, lr = l & 15;
  int n_ = blockIdx.x;
  int cx = n_ & 7, slot = n_ >> 3;
  int m0 = (((slot >> 3) << 3) | cx) * 128;
  int n0 = (slot & 7) * 128;
  int wm = (w >> 1) * 64, wn = (w & 1) * 64;

  f32x4 acc[4][4] = {};

#define STAGE_AB(kt_, buf_)                                                    \
  {                                                                            \
    _Pragma("unroll") for (int i = 0; i < 2; ++i) {                            \
      int c = t + i * 256;                                                     \
      int d = c << 4;                                                          \
      int row = d >> 6, off = d & 63;                                          \
      int soff = off ^ ((row & 3) << 4);                                       \
      gll16(Ctx + (size_t)(m0 + row) * 1024 + (kt_) + (soff >> 1),             \
            (char*)Al[buf_] + d);                                              \
      gll16(Wot + (size_t)(n0 + row) * 1024 + (kt_) + (soff >> 1),             \
            (char*)Bl[buf_] + d);                                              \
    }                                                                          \
  }

  STAGE_AB(0, 0);

  for (int tt = 0; tt < 32; ++tt) {
    int cur = tt & 1;
    if (tt < 31) {
      STAGE_AB((tt + 1) * 32, cur ^ 1);
      WAITV(4);
    } else {
      WAITV(0);
    }
    SCHED0();
    BAR();
    bf16x8 af[4], bfr[4];
#pragma unroll
    for (int mf = 0; mf < 4; ++mf) {
      int row = wm + mf * 16 + lr;
      af[mf] = lds8(Al[cur], (row << 6) + ((lg ^ (row & 3)) << 4));
    }
#pragma unroll
    for (int nf = 0; nf < 4; ++nf) {
      int row = wn + nf * 16 + lr;
      bfr[nf] = lds8(Bl[cur], (row << 6) + ((lg ^ (row & 3)) << 4));
    }
#pragma unroll
    for (int mf = 0; mf < 4; ++mf)
#pragma unroll
      for (int nf = 0; nf < 4; ++nf)
        acc[mf][nf] = __builtin_amdgcn_mfma_f32_16x16x32_bf16(af[mf], bfr[nf], acc[mf][nf], 0, 0, 0);
    BAR();
  }
#undef STAGE_AB

#pragma unroll
  for (int mf = 0; mf < 4; ++mf)
#pragma unroll
    for (int nf = 0; nf < 4; ++nf)
#pragma unroll
      for (int r = 0; r < 4; ++r) {
        int m = m0 + wm + mf * 16 + lg * 4 + r;
        int n = n0 + wn + nf * 16 + lr;
        float v = acc[mf][nf][r] + bo[n] + resid[(size_t)m * 1024 + n];
        preLN[(size_t)m * 1024 + n] = v;
      }
}

// ---------------- K4: LayerNorm (1 wave per row, 4 rows per block) ---------
__global__ __launch_bounds__(256) void layernorm(const float* __restrict__ x,
                                                 const float* __restrict__ gamma,
                                                 const float* __restrict__ beta,
                                                 float* __restrict__ out) {
  int t = threadIdx.x;
  int w = t >> 6, l = t & 63;
  int row = blockIdx.x * 4 + w;
  const float* xr = x + (size_t)row * 1024;
  float4 v[4];
  float s = 0.f, s2 = 0.f;
#pragma unroll
  for (int c = 0; c < 4; ++c) {
    v[c] = *(const float4*)(xr + c * 256 + l * 4);
    s += v[c].x + v[c].y + v[c].z + v[c].w;
    s2 += v[c].x * v[c].x + v[c].y * v[c].y + v[c].z * v[c].z + v[c].w * v[c].w;
  }
#pragma unroll
  for (int m = 1; m < 64; m <<= 1) {
    s += __shfl_xor(s, m);
    s2 += __shfl_xor(s2, m);
  }
  float mu = s * (1.0f / 1024.0f);
  float var = s2 * (1.0f / 1024.0f) - mu * mu;
  float rs = rsqrtf(var + 1e-5f);
  float* orow = out + (size_t)row * 1024;
#pragma unroll
  for (int c = 0; c < 4; ++c) {
    float4 g = *(const float4*)(gamma + c * 256 + l * 4);
    float4 bb = *(const float4*)(beta + c * 256 + l * 4);
    float4 o;
    o.x = (v[c].x - mu) * rs * g.x + bb.x;
    o.y = (v[c].y - mu) * rs * g.y + bb.y;
    o.z = (v[c].z - mu) * rs * g.z + bb.z;
    o.w = (v[c].w - mu) * rs * g.w + bb.w;
    *(float4*)(orow + c * 256 + l * 4) = o;
  }
}

// ---------------- launch ----------------
extern "C" void kernel_launch(void* const* d_in, const int* in_sizes, int n_in,
                              void* d_out, int out_size, void* d_ws, size_t ws_size,
                              hipStream_t stream) {
  const float* Xq = (const float*)d_in[0];
  const float* Xk = (const float*)d_in[1];
  const float* Xv = (const float*)d_in[2];
  const int* Mask = (const int*)d_in[3];
  const float* Wq = (const float*)d_in[4];
  const float* bq = (const float*)d_in[5];
  const float* Wk = (const float*)d_in[6];
  const float* bk = (const float*)d_in[7];
  const float* Wv = (const float*)d_in[8];
  const float* bv = (const float*)d_in[9];
  const float* Wo = (const float*)d_in[10];
  const float* bo = (const float*)d_in[11];
  const float* gamma = (const float*)d_in[12];
  const float* beta = (const float*)d_in[13];

  char* ws = (char*)d_ws;
  u16* Xbf   = (u16*)(ws + 0);            // 48 MiB (aliased by preLN later)
  u16* Wt    = (u16*)(ws + 50331648);     // 8 MiB
  u16* Qs    = (u16*)(ws + 58720256);     // 16 MiB (Q), then K contiguous
  u16* Vt    = (u16*)(ws + 92274688);     // 16 MiB [bh][dv][s]
  u32* Mbits = (u32*)(ws + 109051904);    // 2 MiB
  u16* Ctx   = (u16*)(ws + 111149056);    // 16 MiB
  float* preLN = (float*)(ws + 0);        // 32 MiB, aliases Xbf (dead by then)

  u16* Ks = Qs + 8192ull * 1024;

  float* outp = (float*)d_out;
  float* attn = outp + 8388608ull;

  (void)in_sizes; (void)n_in; (void)out_size; (void)ws_size;

  convert_x<<<dim3(4096, 3), 256, 0, stream>>>(Xq, Xk, Xv, Xbf);
  conv_w<<<dim3(16, 16, 4), 256, 0, stream>>>(Wq, Wk, Wv, Wo, Wt);
  pack_mask<<<32768, 256, 0, stream>>>(Mask, Mbits);
  gemm_qkv<<<dim3(512, 1, 3), 256, 0, stream>>>(Xbf, Wt, bq, bk, bv, Qs, Vt);
  attn_kernel<<<2048, 256, 0, stream>>>(Qs, Ks, Vt, Mbits, attn, Ctx);
  gemm_out<<<512, 256, 0, stream>>>(Ctx, Wt + 3ull * 1048576, bo, Xq, preLN);
  layernorm<<<2048, 256, 0, stream>>>(preLN, gamma, beta, outp);
}

// Round 9
// 406.799 us; speedup vs baseline: 1.2403x; 1.2403x over previous
//
#include <hip/hip_runtime.h>

typedef unsigned short u16;
typedef unsigned int u32;
typedef __bf16 bf16x8 __attribute__((ext_vector_type(8)));
typedef __bf16 bf16x4 __attribute__((ext_vector_type(4)));
typedef u16 u16x8 __attribute__((ext_vector_type(8)));
typedef u32 u32x2 __attribute__((ext_vector_type(2)));
typedef u32 u32x4 __attribute__((ext_vector_type(4)));
typedef float f32x4 __attribute__((ext_vector_type(4)));

#define Ss 2048
#define Hh 16

#define WAITV(n) asm volatile("s_waitcnt vmcnt(" #n ")" ::: "memory")
#define BAR() __builtin_amdgcn_s_barrier()
#define SCHED0() __builtin_amdgcn_sched_barrier(0)

__device__ __forceinline__ void gll16(const void* g, void* l) {
  __builtin_amdgcn_global_load_lds((const __attribute__((address_space(1))) void*)g,
                                   (__attribute__((address_space(3))) void*)l, 16, 0, 0);
}

__device__ __forceinline__ bf16x8 lds8(const u16* base, int byteoff) {
  return __builtin_bit_cast(bf16x8, *(const u16x8*)((const char*)base + byteoff));
}
__device__ __forceinline__ bf16x4 lds4(const u16* base, int byteoff) {
  return __builtin_bit_cast(bf16x4, *(const unsigned long long*)((const char*)base + byteoff));
}
__device__ __forceinline__ bf16x8 g8(const u16* p) {
  return __builtin_bit_cast(bf16x8, *(const u16x8*)p);
}

// ---------------- K0a: convert Q/K/V embeddings f32 -> bf16 (8/thread) -----
__global__ __launch_bounds__(256) void convert_x(const float* __restrict__ xq,
                                                 const float* __restrict__ xk,
                                                 const float* __restrict__ xv,
                                                 u16* __restrict__ dst) {
  int z = blockIdx.y;
  const float* src = (z == 0) ? xq : ((z == 1) ? xk : xv);
  u16* d = dst + (size_t)z * (8192ull * 1024);
  size_t i = ((size_t)blockIdx.x * 256 + threadIdx.x) * 8;
  float4 v0 = *(const float4*)(src + i);
  float4 v1 = *(const float4*)(src + i + 4);
  bf16x8 o;
  o[0] = (__bf16)v0.x; o[1] = (__bf16)v0.y; o[2] = (__bf16)v0.z; o[3] = (__bf16)v0.w;
  o[4] = (__bf16)v1.x; o[5] = (__bf16)v1.y; o[6] = (__bf16)v1.z; o[7] = (__bf16)v1.w;
  *(bf16x8*)(d + i) = o;
}

// ---------------- K0b: transpose + convert weights: Wt[n][k] = W[k][n] -----
__global__ __launch_bounds__(256) void conv_w(const float* __restrict__ wq,
                                              const float* __restrict__ wk,
                                              const float* __restrict__ wv,
                                              const float* __restrict__ wo,
                                              u16* __restrict__ wt) {
  int z = blockIdx.z;
  const float* W = (z == 0) ? wq : (z == 1) ? wk : (z == 2) ? wv : wo;
  u16* O = wt + (size_t)z * (1024ull * 1024);
  __shared__ float tile[64][65];
  int tk = blockIdx.x * 64, tn = blockIdx.y * 64;
  int t = threadIdx.x;
#pragma unroll
  for (int p = 0; p < 4; ++p) {
    int idx = p * 256 + t;
    int r = idx >> 4, c4 = (idx & 15) << 2;
    float4 v = *(const float4*)(W + (size_t)(tk + r) * 1024 + tn + c4);
    tile[r][c4 + 0] = v.x; tile[r][c4 + 1] = v.y;
    tile[r][c4 + 2] = v.z; tile[r][c4 + 3] = v.w;
  }
  __syncthreads();
#pragma unroll
  for (int p = 0; p < 4; ++p) {
    int idx = p * 256 + t;
    int n = idx >> 4, k4 = (idx & 15) << 2;
    bf16x4 o;
    o[0] = (__bf16)tile[k4 + 0][n]; o[1] = (__bf16)tile[k4 + 1][n];
    o[2] = (__bf16)tile[k4 + 2][n]; o[3] = (__bf16)tile[k4 + 3][n];
    *(bf16x4*)(O + (size_t)(tn + n) * 1024 + tk + k4) = o;
  }
}

// ---------------- K0c: pack mask int32 -> bitmask (2/thread) ----------------
__global__ __launch_bounds__(256) void pack_mask(const int* __restrict__ m,
                                                 u32* __restrict__ bits) {
  size_t base = (size_t)blockIdx.x * 512;
  int t = threadIdx.x;
  int w = t >> 6, lane = t & 63;
  bool v0 = (m[base + t] != 0);
  bool v1 = (m[base + 256 + t] != 0);
  unsigned long long b0 = __ballot(v0);
  unsigned long long b1 = __ballot(v1);
  size_t wbase = (base >> 5) + (w << 1);
  if (lane == 0) {
    bits[wbase] = (u32)b0;
    bits[wbase + 8] = (u32)b1;
  } else if (lane == 32) {
    bits[wbase + 1] = (u32)(b0 >> 32);
    bits[wbase + 9] = (u32)(b1 >> 32);
  }
}

// ---------------- K1: QKV projection GEMM (counted-vmcnt + XCD swizzle) ----
// z=0 -> Q [bh][s][dk] scaled by (1/8)*log2(e), z=1 -> K [bh][s][dk],
// z=2 -> V transposed [bh][dv][s]
__global__ __launch_bounds__(256) void gemm_qkv(const u16* __restrict__ Xbf,
                                                const u16* __restrict__ Wt,
                                                const float* __restrict__ bq,
                                                const float* __restrict__ bk,
                                                const float* __restrict__ bv,
                                                u16* __restrict__ OutQK,
                                                u16* __restrict__ Vt) {
  int z = blockIdx.z;
  const u16* A = Xbf + (size_t)z * (8192ull * 1024);
  const u16* Bw = Wt + (size_t)z * (1024ull * 1024);
  const float* bias = (z == 0) ? bq : ((z == 1) ? bk : bv);
  u16* O = OutQK + (size_t)z * (8192ull * 1024);
  float scale = (z == 0) ? (0.125f * 1.4426950408889634f) : 1.0f;

  __shared__ __attribute__((aligned(16))) u16 Al[2][128 * 32];
  __shared__ __attribute__((aligned(16))) u16 Bl[2][128 * 32];

  int t = threadIdx.x, w = t >> 6, l = t & 63, lg = l >> 4, lr = l & 15;
  int n_ = blockIdx.x;
  int cx = n_ & 7, slot = n_ >> 3;
  int m0 = (((slot >> 3) << 3) | cx) * 128;
  int n0 = (slot & 7) * 128;
  int wm = (w >> 1) * 64, wn = (w & 1) * 64;

  f32x4 acc[4][4] = {};

#define STAGE_AB(kt_, buf_)                                                    \
  {                                                                            \
    _Pragma("unroll") for (int i = 0; i < 2; ++i) {                            \
      int c = t + i * 256;                                                     \
      int d = c << 4;                                                          \
      int row = d >> 6, off = d & 63;                                          \
      int soff = off ^ ((row & 3) << 4);                                       \
      gll16(A + (size_t)(m0 + row) * 1024 + (kt_) + (soff >> 1),               \
            (char*)Al[buf_] + d);                                              \
      gll16(Bw + (size_t)(n0 + row) * 1024 + (kt_) + (soff >> 1),              \
            (char*)Bl[buf_] + d);                                              \
    }                                                                          \
  }

  STAGE_AB(0, 0);

  for (int tt = 0; tt < 32; ++tt) {
    int cur = tt & 1;
    if (tt < 31) {
      STAGE_AB((tt + 1) * 32, cur ^ 1);
      WAITV(4);
    } else {
      WAITV(0);
    }
    SCHED0();
    BAR();
    bf16x8 af[4], bfr[4];
#pragma unroll
    for (int mf = 0; mf < 4; ++mf) {
      int row = wm + mf * 16 + lr;
      af[mf] = lds8(Al[cur], (row << 6) + ((lg ^ (row & 3)) << 4));
    }
#pragma unroll
    for (int nf = 0; nf < 4; ++nf) {
      int row = wn + nf * 16 + lr;
      bfr[nf] = lds8(Bl[cur], (row << 6) + ((lg ^ (row & 3)) << 4));
    }
#pragma unroll
    for (int mf = 0; mf < 4; ++mf)
#pragma unroll
      for (int nf = 0; nf < 4; ++nf)
        acc[mf][nf] = __builtin_amdgcn_mfma_f32_16x16x32_bf16(af[mf], bfr[nf], acc[mf][nf], 0, 0, 0);
    BAR();
  }
#undef STAGE_AB

  if (z == 2) {
#pragma unroll
    for (int mf = 0; mf < 4; ++mf)
#pragma unroll
      for (int nf = 0; nf < 4; ++nf) {
        int m = m0 + wm + mf * 16 + lg * 4;
        int n = n0 + wn + nf * 16 + lr;
        bf16x4 ov;
#pragma unroll
        for (int r = 0; r < 4; ++r) ov[r] = (__bf16)(acc[mf][nf][r] + bias[n]);
        int b_ = m >> 11, s_ = m & 2047, hh = n >> 6, dd = n & 63;
        *(bf16x4*)(Vt + (((size_t)(b_ * 16 + hh)) * 64 + dd) * 2048 + s_) = ov;
      }
  } else {
#pragma unroll
    for (int mf = 0; mf < 4; ++mf)
#pragma unroll
      for (int nf = 0; nf < 4; ++nf)
#pragma unroll
        for (int r = 0; r < 4; ++r) {
          int m = m0 + wm + mf * 16 + lg * 4 + r;
          int n = n0 + wn + nf * 16 + lr;
          float v = (acc[mf][nf][r] + bias[n]) * scale;
          int b_ = m >> 11, s_ = m & 2047, hh = n >> 6, dd = n & 63;
          *(__bf16*)&O[(((size_t)(b_ * 16 + hh)) * 2048 + s_) * 64 + dd] = (__bf16)v;
        }
  }
}

// ---------------- K2: staged fused attention ----------------
// pass 0: KC=128 K-tiles; pass 1: KC=64 with LDS-redistributed attn stores
// (each nt store instruction covers 4 rows x 256B contiguous = full lines)
__global__ __launch_bounds__(256, 4) void attn_kernel(const u16* __restrict__ Qs,
                                                      const u16* __restrict__ Ks,
                                                      const u16* __restrict__ Vt,
                                                      const u32* __restrict__ Mbits,
                                                      float* __restrict__ attn,
                                                      u16* __restrict__ Ctx) {
  int bid = blockIdx.x;  // 2048 blocks; one head's 32 q-blocks stay on one XCD
  int xcd = bid & 7, j = bid >> 3;
  int bh = xcd * 8 + (j >> 5);
  int q0 = (j & 31) * 64;
  int b = bh >> 4, h = bh & 15;
  int t = threadIdx.x;
  int w = t >> 6, l = t & 63, lg = l >> 4, lr = l & 15;

  const u16* Qb = Qs + (size_t)bh * (Ss * 64);
  const u16* Kb = Ks + (size_t)bh * (Ss * 64);
  const u16* Vb = Vt + (size_t)bh * (64 * Ss);
  int qrow = w * 16 + lr;
  const u32* Mrow = Mbits + ((size_t)b * Ss + q0 + qrow) * 64;

  // flat 40 KB arena:
  //  pass 0: K dbuf [2][16KB] @ 0
  //  pass 1: K dbuf [2][8KB] @ 0, V dbuf [2][8KB] @ 16K, P @ 32K
  __shared__ __attribute__((aligned(16))) char SMb[40960];
  u16* Pl = (u16*)(SMb + 32768);

  int srow = t >> 3;
  int skoff = (((t & 7) << 4) ^ ((srow & 7) << 4));

#define STAGE_K2(kc_, buf_)                                                    \
  {                                                                            \
    _Pragma("unroll") for (int i = 0; i < 4; ++i)                              \
        gll16(Kb + (size_t)((kc_) + srow + 32 * i) * 64 + (skoff >> 1),        \
              SMb + (buf_)*16384 + i * 4096 + (t << 4));                       \
  }
#define STAGE_K(kc_, buf_)                                                     \
  {                                                                            \
    gll16(Kb + (size_t)((kc_) + srow) * 64 + (skoff >> 1),                     \
          SMb + (buf_)*8192 + (t << 4));                                       \
    gll16(Kb + (size_t)((kc_) + srow + 32) * 64 + (skoff >> 1),                \
          SMb + (buf_)*8192 + (t << 4) + 4096);                                \
  }
#define STAGE_V(kc_, buf_)                                                     \
  {                                                                            \
    gll16(Vb + (size_t)srow * 2048 + (kc_) + (skoff >> 1),                     \
          SMb + 16384 + (buf_)*8192 + (t << 4));                               \
    gll16(Vb + (size_t)(srow + 32) * 2048 + (kc_) + (skoff >> 1),              \
          SMb + 16384 + (buf_)*8192 + (t << 4) + 4096);                        \
  }

  bf16x8 qf[2];
  {
    const u16* qr = Qb + (size_t)(q0 + qrow) * 64;
    qf[0] = g8(qr + lg * 8);
    qf[1] = g8(qr + 32 + lg * 8);
  }

  int swzq = (lr & 7) << 4;

  // ================= pass 0: rowsums (KC=128) =================
  float rsum = 0.f;
  {
    STAGE_K2(0, 0);
    u32x4 mq = *(const u32x4*)(Mrow);
    u32x4 mqn;
    for (int tt = 0; tt < 16; ++tt) {
      int cur = tt & 1;
      if (tt < 15) {
        STAGE_K2((tt + 1) * 128, cur ^ 1);
        mqn = *(const u32x4*)(Mrow + ((tt + 1) << 2));
        WAITV(5);
      } else {
        WAITV(0);
      }
      SCHED0();
      BAR();
      const u16* Kc = (const u16*)(SMb + cur * 16384);
#pragma unroll
      for (int nf = 0; nf < 8; ++nf) {
        int krow = nf * 16 + lr;
        int base = krow << 7, swz = (krow & 7) << 4;
        f32x4 sc = {};
        __builtin_amdgcn_s_setprio(1);
        sc = __builtin_amdgcn_mfma_f32_16x16x32_bf16(
            lds8(Kc, base + ((lg << 4) ^ swz)), qf[0], sc, 0, 0, 0);
        sc = __builtin_amdgcn_mfma_f32_16x16x32_bf16(
            lds8(Kc, base + ((64 + (lg << 4)) ^ swz)), qf[1], sc, 0, 0, 0);
        __builtin_amdgcn_s_setprio(0);
        u32 mb = mq[nf >> 1] >> (((nf & 1) << 4) + (lg << 2));
#pragma unroll
        for (int r = 0; r < 4; ++r)
          rsum += ((mb >> r) & 1) ? 0.f : __builtin_amdgcn_exp2f(sc[r]);
      }
      mq = mqn;
      BAR();
    }
  }
  float inv;
  {
    float s = rsum;
    s += __shfl_xor(s, 16);
    s += __shfl_xor(s, 32);
    inv = 1.0f / s;
  }

  // ================= pass 1: write attention + P.V (KC=64) ============
  // store path: P goes to LDS (bf16, also used for PV); read back per-row
  // segments so each nt-store instruction covers 4 rows x 256B contiguous.
  float* abase = attn + ((size_t)bh * Ss + q0 + w * 16) * Ss;  // wave's 16 rows
  int rsub = l >> 4;     // row sub-index 0..3 within a 4-row group
  int kch = (l & 15);    // 16B k-chunk 0..15 (covers 64 k per row)
  f32x4 ctx[4] = {};
  {
    STAGE_K(0, 0);
    STAGE_V(0, 0);
    u32x2 mq = *(const u32x2*)(Mrow);
    u32x2 mqn;
    for (int tt = 0; tt < 32; ++tt) {
      int cur = tt & 1;
      if (tt == 0) {
        STAGE_K(64, 1);
        STAGE_V(64, 1);
        mqn = *(const u32x2*)(Mrow + 2);
        WAITV(5);
      } else if (tt < 31) {
        STAGE_K((tt + 1) * 64, cur ^ 1);
        STAGE_V((tt + 1) * 64, cur ^ 1);
        mqn = *(const u32x2*)(Mrow + ((tt + 1) << 1));
        WAITV(9);
      } else {
        WAITV(4);
      }
      SCHED0();
      BAR();
      const u16* Kc = (const u16*)(SMb + cur * 8192);
      const u16* Vc = (const u16*)(SMb + 16384 + cur * 8192);
      int kc = tt * 64;
#pragma unroll
      for (int nf = 0; nf < 4; ++nf) {
        int krow = nf * 16 + lr;
        int base = krow << 7, swz = (krow & 7) << 4;
        f32x4 sc = {};
        __builtin_amdgcn_s_setprio(1);
        sc = __builtin_amdgcn_mfma_f32_16x16x32_bf16(
            lds8(Kc, base + ((lg << 4) ^ swz)), qf[0], sc, 0, 0, 0);
        sc = __builtin_amdgcn_mfma_f32_16x16x32_bf16(
            lds8(Kc, base + ((64 + (lg << 4)) ^ swz)), qf[1], sc, 0, 0, 0);
        __builtin_amdgcn_s_setprio(0);
        u32 mb = mq[nf >> 1] >> (((nf & 1) << 4) + (lg << 2));
        f32x4 p4;
#pragma unroll
        for (int r = 0; r < 4; ++r)
          p4[r] = (((mb >> r) & 1) ? 0.f : __builtin_amdgcn_exp2f(sc[r])) * inv;
        bf16x4 pb;
#pragma unroll
        for (int r = 0; r < 4; ++r) pb[r] = (__bf16)p4[r];
        *(bf16x4*)((char*)Pl + (qrow << 7) + (((nf << 5) + (lg << 3)) ^ swzq)) = pb;
      }
      // redistribute: wave-private rows, 4 iterations of 4 rows x 256B
#pragma unroll
      for (int rb = 0; rb < 4; ++rb) {
        int rrow = rb * 4 + rsub;                 // 0..15 within wave tile
        int R = w * 16 + rrow;
        bf16x4 pv4 = lds4(Pl, (R << 7) + ((kch << 3) ^ ((R & 7) << 4)));
        f32x4 o4;
#pragma unroll
        for (int r = 0; r < 4; ++r) o4[r] = (float)pv4[r];
        __builtin_nontemporal_store(
            o4, (f32x4*)(abase + (size_t)rrow * Ss + kc + kch * 4));
      }
      // P.V over this 64-k tile
      __builtin_amdgcn_s_setprio(1);
#pragma unroll
      for (int ks = 0; ks < 2; ++ks) {
        bf16x8 pf = lds8(Pl, (qrow << 7) + (((ks << 6) + (lg << 4)) ^ swzq));
#pragma unroll
        for (int nfo = 0; nfo < 4; ++nfo) {
          int vr = nfo * 16 + lr;
          bf16x8 vf = lds8(Vc,
                           (vr << 7) + (((ks << 6) + (lg << 4)) ^ ((vr & 7) << 4)));
          ctx[nfo] = __builtin_amdgcn_mfma_f32_16x16x32_bf16(pf, vf, ctx[nfo], 0, 0, 0);
        }
      }
      __builtin_amdgcn_s_setprio(0);
      mq = mqn;
      BAR();
    }
  }
#undef STAGE_K2
#undef STAGE_K
#undef STAGE_V

  // write context: Ctx[b][s][h*64+dd]
#pragma unroll
  for (int nfo = 0; nfo < 4; ++nfo)
#pragma unroll
    for (int r = 0; r < 4; ++r) {
      int qr2 = w * 16 + lg * 4 + r;
      int dd = nfo * 16 + lr;
      *(__bf16*)&Ctx[((size_t)b * Ss + q0 + qr2) * (Hh * 64) + h * 64 + dd] =
          (__bf16)ctx[nfo][r];
    }
}

// ---------------- K3: output projection + bias + residual (XCD swizzle) ----
__global__ __launch_bounds__(256) void gemm_out(const u16* __restrict__ Ctx,
                                                const u16* __restrict__ Wot,
                                                const float* __restrict__ bo,
                                                const float* __restrict__ resid,
                                                float* __restrict__ preLN) {
  __shared__ __attribute__((aligned(16))) u16 Al[2][128 * 32];
  __shared__ __attribute__((aligned(16))) u16 Bl[2][128 * 32];

  int t = threadIdx.x, w = t >> 6, l = t & 63, lg = l >> 4, lr = l & 15;
  int n_ = blockIdx.x;
  int cx = n_ & 7, slot = n_ >> 3;
  int m0 = (((slot >> 3) << 3) | cx) * 128;
  int n0 = (slot & 7) * 128;
  int wm = (w >> 1) * 64, wn = (w & 1) * 64;

  f32x4 acc[4][4] = {};

#define STAGE_AB(kt_, buf_)                                                    \
  {                                                                            \
    _Pragma("unroll") for (int i = 0; i < 2; ++i) {                            \
      int c = t + i * 256;                                                     \
      int d = c << 4;                                                          \
      int row = d >> 6, off = d & 63;                                          \
      int soff = off ^ ((row & 3) << 4);                                       \
      gll16(Ctx + (size_t)(m0 + row) * 1024 + (kt_) + (soff >> 1),             \
            (char*)Al[buf_] + d);                                              \
      gll16(Wot + (size_t)(n0 + row) * 1024 + (kt_) + (soff >> 1),             \
            (char*)Bl[buf_] + d);                                              \
    }                                                                          \
  }

  STAGE_AB(0, 0);

  for (int tt = 0; tt < 32; ++tt) {
    int cur = tt & 1;
    if (tt < 31) {
      STAGE_AB((tt + 1) * 32, cur ^ 1);
      WAITV(4);
    } else {
      WAITV(0);
    }
    SCHED0();
    BAR();
    bf16x8 af[4], bfr[4];
#pragma unroll
    for (int mf = 0; mf < 4; ++mf) {
      int row = wm + mf * 16 + lr;
      af[mf] = lds8(Al[cur], (row << 6) + ((lg ^ (row & 3)) << 4));
    }
#pragma unroll
    for (int nf = 0; nf < 4; ++nf) {
      int row = wn + nf * 16 + lr;
      bfr[nf] = lds8(Bl[cur], (row << 6) + ((lg ^ (row & 3)) << 4));
    }
#pragma unroll
    for (int mf = 0; mf < 4; ++mf)
#pragma unroll
      for (int nf = 0; nf < 4; ++nf)
        acc[mf][nf] = __builtin_amdgcn_mfma_f32_16x16x32_bf16(af[mf], bfr[nf], acc[mf][nf], 0, 0, 0);
    BAR();
  }
#undef STAGE_AB

#pragma unroll
  for (int mf = 0; mf < 4; ++mf)
#pragma unroll
    for (int nf = 0; nf < 4; ++nf)
#pragma unroll
      for (int r = 0; r < 4; ++r) {
        int m = m0 + wm + mf * 16 + lg * 4 + r;
        int n = n0 + wn + nf * 16 + lr;
        float v = acc[mf][nf][r] + bo[n] + resid[(size_t)m * 1024 + n];
        preLN[(size_t)m * 1024 + n] = v;
      }
}

// ---------------- K4: LayerNorm (1 wave per row, 4 rows per block) ---------
__global__ __launch_bounds__(256) void layernorm(const float* __restrict__ x,
                                                 const float* __restrict__ gamma,
                                                 const float* __restrict__ beta,
                                                 float* __restrict__ out) {
  int t = threadIdx.x;
  int w = t >> 6, l = t & 63;
  int row = blockIdx.x * 4 + w;
  const float* xr = x + (size_t)row * 1024;
  float4 v[4];
  float s = 0.f, s2 = 0.f;
#pragma unroll
  for (int c = 0; c < 4; ++c) {
    v[c] = *(const float4*)(xr + c * 256 + l * 4);
    s += v[c].x + v[c].y + v[c].z + v[c].w;
    s2 += v[c].x * v[c].x + v[c].y * v[c].y + v[c].z * v[c].z + v[c].w * v[c].w;
  }
#pragma unroll
  for (int m = 1; m < 64; m <<= 1) {
    s += __shfl_xor(s, m);
    s2 += __shfl_xor(s2, m);
  }
  float mu = s * (1.0f / 1024.0f);
  float var = s2 * (1.0f / 1024.0f) - mu * mu;
  float rs = rsqrtf(var + 1e-5f);
  float* orow = out + (size_t)row * 1024;
#pragma unroll
  for (int c = 0; c < 4; ++c) {
    float4 g = *(const float4*)(gamma + c * 256 + l * 4);
    float4 bb = *(const float4*)(beta + c * 256 + l * 4);
    float4 o;
    o.x = (v[c].x - mu) * rs * g.x + bb.x;
    o.y = (v[c].y - mu) * rs * g.y + bb.y;
    o.z = (v[c].z - mu) * rs * g.z + bb.z;
    o.w = (v[c].w - mu) * rs * g.w + bb.w;
    *(float4*)(orow + c * 256 + l * 4) = o;
  }
}

// ---------------- launch ----------------
extern "C" void kernel_launch(void* const* d_in, const int* in_sizes, int n_in,
                              void* d_out, int out_size, void* d_ws, size_t ws_size,
                              hipStream_t stream) {
  const float* Xq = (const float*)d_in[0];
  const float* Xk = (const float*)d_in[1];
  const float* Xv = (const float*)d_in[2];
  const int* Mask = (const int*)d_in[3];
  const float* Wq = (const float*)d_in[4];
  const float* bq = (const float*)d_in[5];
  const float* Wk = (const float*)d_in[6];
  const float* bk = (const float*)d_in[7];
  const float* Wv = (const float*)d_in[8];
  const float* bv = (const float*)d_in[9];
  const float* Wo = (const float*)d_in[10];
  const float* bo = (const float*)d_in[11];
  const float* gamma = (const float*)d_in[12];
  const float* beta = (const float*)d_in[13];

  char* ws = (char*)d_ws;
  u16* Xbf   = (u16*)(ws + 0);            // 48 MiB (aliased by preLN later)
  u16* Wt    = (u16*)(ws + 50331648);     // 8 MiB
  u16* Qs    = (u16*)(ws + 58720256);     // 16 MiB (Q), then K contiguous
  u16* Vt    = (u16*)(ws + 92274688);     // 16 MiB [bh][dv][s]
  u32* Mbits = (u32*)(ws + 109051904);    // 2 MiB
  u16* Ctx   = (u16*)(ws + 111149056);    // 16 MiB
  float* preLN = (float*)(ws + 0);        // 32 MiB, aliases Xbf (dead by then)

  u16* Ks = Qs + 8192ull * 1024;

  float* outp = (float*)d_out;
  float* attn = outp + 8388608ull;

  (void)in_sizes; (void)n_in; (void)out_size; (void)ws_size;

  convert_x<<<dim3(4096, 3), 256, 0, stream>>>(Xq, Xk, Xv, Xbf);
  conv_w<<<dim3(16, 16, 4), 256, 0, stream>>>(Wq, Wk, Wv, Wo, Wt);
  pack_mask<<<32768, 256, 0, stream>>>(Mask, Mbits);
  gemm_qkv<<<dim3(512, 1, 3), 256, 0, stream>>>(Xbf, Wt, bq, bk, bv, Qs, Vt);
  attn_kernel<<<2048, 256, 0, stream>>>(Qs, Ks, Vt, Mbits, attn, Ctx);
  gemm_out<<<512, 256, 0, stream>>>(Ctx, Wt + 3ull * 1048576, bo, Xq, preLN);
  layernorm<<<2048, 256, 0, stream>>>(preLN, gamma, beta, outp);
}

// Round 10
// 390.480 us; speedup vs baseline: 1.2921x; 1.0418x over previous
//
#include <hip/hip_runtime.h>

typedef unsigned short u16;
typedef unsigned int u32;
typedef __bf16 bf16x8 __attribute__((ext_vector_type(8)));
typedef __bf16 bf16x4 __attribute__((ext_vector_type(4)));
typedef u16 u16x8 __attribute__((ext_vector_type(8)));
typedef u32 u32x2 __attribute__((ext_vector_type(2)));
typedef u32 u32x4 __attribute__((ext_vector_type(4)));
typedef float f32x4 __attribute__((ext_vector_type(4)));

#define Ss 2048
#define Hh 16

#define WAITV(n) asm volatile("s_waitcnt vmcnt(" #n ")" ::: "memory")
#define BAR() __builtin_amdgcn_s_barrier()
#define SCHED0() __builtin_amdgcn_sched_barrier(0)

__device__ __forceinline__ void gll16(const void* g, void* l) {
  __builtin_amdgcn_global_load_lds((const __attribute__((address_space(1))) void*)g,
                                   (__attribute__((address_space(3))) void*)l, 16, 0, 0);
}

__device__ __forceinline__ bf16x8 lds8(const u16* base, int byteoff) {
  return __builtin_bit_cast(bf16x8, *(const u16x8*)((const char*)base + byteoff));
}
__device__ __forceinline__ bf16x4 lds4(const u16* base, int byteoff) {
  return __builtin_bit_cast(bf16x4, *(const unsigned long long*)((const char*)base + byteoff));
}
__device__ __forceinline__ bf16x8 g8(const u16* p) {
  return __builtin_bit_cast(bf16x8, *(const u16x8*)p);
}
__device__ __forceinline__ u16 bfbits(float f) {
  return __builtin_bit_cast(u16, (__bf16)f);
}

// ---------------- K0a: convert Q/K/V embeddings f32 -> bf16 (8/thread) -----
__global__ __launch_bounds__(256) void convert_x(const float* __restrict__ xq,
                                                 const float* __restrict__ xk,
                                                 const float* __restrict__ xv,
                                                 u16* __restrict__ dst) {
  int z = blockIdx.y;
  const float* src = (z == 0) ? xq : ((z == 1) ? xk : xv);
  u16* d = dst + (size_t)z * (8192ull * 1024);
  size_t i = ((size_t)blockIdx.x * 256 + threadIdx.x) * 8;
  float4 v0 = *(const float4*)(src + i);
  float4 v1 = *(const float4*)(src + i + 4);
  bf16x8 o;
  o[0] = (__bf16)v0.x; o[1] = (__bf16)v0.y; o[2] = (__bf16)v0.z; o[3] = (__bf16)v0.w;
  o[4] = (__bf16)v1.x; o[5] = (__bf16)v1.y; o[6] = (__bf16)v1.z; o[7] = (__bf16)v1.w;
  *(bf16x8*)(d + i) = o;
}

// ---------------- K0b: transpose + convert weights: Wt[n][k] = W[k][n] -----
__global__ __launch_bounds__(256) void conv_w(const float* __restrict__ wq,
                                              const float* __restrict__ wk,
                                              const float* __restrict__ wv,
                                              const float* __restrict__ wo,
                                              u16* __restrict__ wt) {
  int z = blockIdx.z;
  const float* W = (z == 0) ? wq : (z == 1) ? wk : (z == 2) ? wv : wo;
  u16* O = wt + (size_t)z * (1024ull * 1024);
  __shared__ float tile[64][65];
  int tk = blockIdx.x * 64, tn = blockIdx.y * 64;
  int t = threadIdx.x;
#pragma unroll
  for (int p = 0; p < 4; ++p) {
    int idx = p * 256 + t;
    int r = idx >> 4, c4 = (idx & 15) << 2;
    float4 v = *(const float4*)(W + (size_t)(tk + r) * 1024 + tn + c4);
    tile[r][c4 + 0] = v.x; tile[r][c4 + 1] = v.y;
    tile[r][c4 + 2] = v.z; tile[r][c4 + 3] = v.w;
  }
  __syncthreads();
#pragma unroll
  for (int p = 0; p < 4; ++p) {
    int idx = p * 256 + t;
    int n = idx >> 4, k4 = (idx & 15) << 2;
    bf16x4 o;
    o[0] = (__bf16)tile[k4 + 0][n]; o[1] = (__bf16)tile[k4 + 1][n];
    o[2] = (__bf16)tile[k4 + 2][n]; o[3] = (__bf16)tile[k4 + 3][n];
    *(bf16x4*)(O + (size_t)(tn + n) * 1024 + tk + k4) = o;
  }
}

// ---------------- K0c: pack mask int32 -> bitmask (2/thread) ----------------
__global__ __launch_bounds__(256) void pack_mask(const int* __restrict__ m,
                                                 u32* __restrict__ bits) {
  size_t base = (size_t)blockIdx.x * 512;
  int t = threadIdx.x;
  int w = t >> 6, lane = t & 63;
  bool v0 = (m[base + t] != 0);
  bool v1 = (m[base + 256 + t] != 0);
  unsigned long long b0 = __ballot(v0);
  unsigned long long b1 = __ballot(v1);
  size_t wbase = (base >> 5) + (w << 1);
  if (lane == 0) {
    bits[wbase] = (u32)b0;
    bits[wbase + 8] = (u32)b1;
  } else if (lane == 32) {
    bits[wbase + 1] = (u32)(b0 >> 32);
    bits[wbase + 9] = (u32)(b1 >> 32);
  }
}

// ---------------- K1: QKV projection GEMM (counted-vmcnt + XCD swizzle) ----
// z=0 -> Q [bh][s][dk] scaled by (1/8)*log2(e), z=1 -> K [bh][s][dk],
// z=2 -> V transposed [bh][dv][s]
// Epilogue redistributes output through LDS for full-line 16B stores.
__global__ __launch_bounds__(256) void gemm_qkv(const u16* __restrict__ Xbf,
                                                const u16* __restrict__ Wt,
                                                const float* __restrict__ bq,
                                                const float* __restrict__ bk,
                                                const float* __restrict__ bv,
                                                u16* __restrict__ OutQK,
                                                u16* __restrict__ Vt) {
  int z = blockIdx.z;
  const u16* A = Xbf + (size_t)z * (8192ull * 1024);
  const u16* Bw = Wt + (size_t)z * (1024ull * 1024);
  const float* bias = (z == 0) ? bq : ((z == 1) ? bk : bv);
  u16* O = OutQK + (size_t)z * (8192ull * 1024);
  float scale = (z == 0) ? (0.125f * 1.4426950408889634f) : 1.0f;

  // flat 32 KB arena: A dbuf @0 (u16 units: buf*4096), B dbuf @8192
  __shared__ __attribute__((aligned(16))) u16 SM[16384];

  int t = threadIdx.x, w = t >> 6, l = t & 63, lg = l >> 4, lr = l & 15;
  int n_ = blockIdx.x;
  int cx = n_ & 7, slot = n_ >> 3;
  int m0 = (((slot >> 3) << 3) | cx) * 128;
  int n0 = (slot & 7) * 128;
  int wm = (w >> 1) * 64, wn = (w & 1) * 64;

  f32x4 acc[4][4] = {};

#define STAGE_AB(kt_, buf_)                                                    \
  {                                                                            \
    _Pragma("unroll") for (int i = 0; i < 2; ++i) {                            \
      int c = t + i * 256;                                                     \
      int d = c << 4;                                                          \
      int row = d >> 6, off = d & 63;                                          \
      int soff = off ^ ((row & 3) << 4);                                       \
      gll16(A + (size_t)(m0 + row) * 1024 + (kt_) + (soff >> 1),               \
            (char*)SM + (buf_)*8192 + d);                                      \
      gll16(Bw + (size_t)(n0 + row) * 1024 + (kt_) + (soff >> 1),              \
            (char*)SM + 16384 + (buf_)*8192 + d);                              \
    }                                                                          \
  }

  STAGE_AB(0, 0);

  for (int tt = 0; tt < 32; ++tt) {
    int cur = tt & 1;
    if (tt < 31) {
      STAGE_AB((tt + 1) * 32, cur ^ 1);
      WAITV(4);
    } else {
      WAITV(0);
    }
    SCHED0();
    BAR();
    const u16* Ac = SM + cur * 4096;
    const u16* Bc = SM + 8192 + cur * 4096;
    bf16x8 af[4], bfr[4];
#pragma unroll
    for (int mf = 0; mf < 4; ++mf) {
      int row = wm + mf * 16 + lr;
      af[mf] = lds8(Ac, (row << 6) + ((lg ^ (row & 3)) << 4));
    }
#pragma unroll
    for (int nf = 0; nf < 4; ++nf) {
      int row = wn + nf * 16 + lr;
      bfr[nf] = lds8(Bc, (row << 6) + ((lg ^ (row & 3)) << 4));
    }
#pragma unroll
    for (int mf = 0; mf < 4; ++mf)
#pragma unroll
      for (int nf = 0; nf < 4; ++nf)
        acc[mf][nf] = __builtin_amdgcn_mfma_f32_16x16x32_bf16(af[mf], bfr[nf], acc[mf][nf], 0, 0, 0);
    BAR();
  }
#undef STAGE_AB

  // -------- epilogue: redistribute through SM (32 KB free) --------
  if (z == 2) {
    // stage transposed tile TL[n'][m'] (128x128 u16), row-XOR-swizzled
#pragma unroll
    for (int mf = 0; mf < 4; ++mf)
#pragma unroll
      for (int nf = 0; nf < 4; ++nf) {
        int mloc = wm + mf * 16 + lg * 4;           // m' base (mult of 4)
        int nloc = wn + nf * 16 + lr;               // n' row
        bf16x4 ov;
        int n = n0 + nloc;
#pragma unroll
        for (int r = 0; r < 4; ++r) ov[r] = (__bf16)(acc[mf][nf][r] + bias[n]);
        *(bf16x4*)&SM[nloc * 128 + (mloc ^ ((nloc & 7) << 3))] = ov;
      }
    BAR();
    int b_ = m0 >> 11, s0_ = m0 & 2047;
#pragma unroll
    for (int i = 0; i < 8; ++i) {
      int idx = i * 256 + t;
      int nloc = idx >> 4, c = idx & 15;
      u16x8 val = *(const u16x8*)&SM[nloc * 128 + (((c ^ (nloc & 7)) << 3))];
      int n = n0 + nloc, hh = n >> 6, dd = n & 63;
      *(u16x8*)&Vt[(((size_t)(b_ * 16 + hh)) * 64 + dd) * 2048 + s0_ + c * 8] = val;
    }
  } else {
    // stage TL[row_m][n'] (128x128 u16), row-XOR-swizzled
#pragma unroll
    for (int mf = 0; mf < 4; ++mf)
#pragma unroll
      for (int nf = 0; nf < 4; ++nf)
#pragma unroll
        for (int r = 0; r < 4; ++r) {
          int row = wm + mf * 16 + lg * 4 + r;
          int col = wn + nf * 16 + lr;
          float v = (acc[mf][nf][r] + bias[n0 + col]) * scale;
          SM[row * 128 + (col ^ ((row & 7) << 3))] = bfbits(v);
        }
    BAR();
    int b_ = m0 >> 11, s0_ = m0 & 2047;
#pragma unroll
    for (int i = 0; i < 8; ++i) {
      int idx = i * 256 + t;
      int row = idx >> 4, c = idx & 15;
      u16x8 val = *(const u16x8*)&SM[row * 128 + (((c ^ (row & 7)) << 3))];
      int n = n0 + c * 8, hh = n >> 6, dd = n & 63;
      *(u16x8*)&O[(((size_t)(b_ * 16 + hh)) * 2048 + s0_ + row) * 64 + dd] = val;
    }
  }
}

// ---------------- K2: staged fused attention ----------------
// pass 0: KC=128 K-tiles; pass 1: KC=64 with LDS-redistributed attn stores;
// Ctx written coalesced via LDS at the end.
__global__ __launch_bounds__(256, 4) void attn_kernel(const u16* __restrict__ Qs,
                                                      const u16* __restrict__ Ks,
                                                      const u16* __restrict__ Vt,
                                                      const u32* __restrict__ Mbits,
                                                      float* __restrict__ attn,
                                                      u16* __restrict__ Ctx) {
  int bid = blockIdx.x;  // 2048 blocks; one head's 32 q-blocks stay on one XCD
  int xcd = bid & 7, j = bid >> 3;
  int bh = xcd * 8 + (j >> 5);
  int q0 = (j & 31) * 64;
  int b = bh >> 4, h = bh & 15;
  int t = threadIdx.x;
  int w = t >> 6, l = t & 63, lg = l >> 4, lr = l & 15;

  const u16* Qb = Qs + (size_t)bh * (Ss * 64);
  const u16* Kb = Ks + (size_t)bh * (Ss * 64);
  const u16* Vb = Vt + (size_t)bh * (64 * Ss);
  int qrow = w * 16 + lr;
  const u32* Mrow = Mbits + ((size_t)b * Ss + q0 + qrow) * 64;

  __shared__ __attribute__((aligned(16))) char SMb[40960];
  u16* Pl = (u16*)(SMb + 32768);

  int srow = t >> 3;
  int skoff = (((t & 7) << 4) ^ ((srow & 7) << 4));

#define STAGE_K2(kc_, buf_)                                                    \
  {                                                                            \
    _Pragma("unroll") for (int i = 0; i < 4; ++i)                              \
        gll16(Kb + (size_t)((kc_) + srow + 32 * i) * 64 + (skoff >> 1),        \
              SMb + (buf_)*16384 + i * 4096 + (t << 4));                       \
  }
#define STAGE_K(kc_, buf_)                                                     \
  {                                                                            \
    gll16(Kb + (size_t)((kc_) + srow) * 64 + (skoff >> 1),                     \
          SMb + (buf_)*8192 + (t << 4));                                       \
    gll16(Kb + (size_t)((kc_) + srow + 32) * 64 + (skoff >> 1),                \
          SMb + (buf_)*8192 + (t << 4) + 4096);                                \
  }
#define STAGE_V(kc_, buf_)                                                     \
  {                                                                            \
    gll16(Vb + (size_t)srow * 2048 + (kc_) + (skoff >> 1),                     \
          SMb + 16384 + (buf_)*8192 + (t << 4));                               \
    gll16(Vb + (size_t)(srow + 32) * 2048 + (kc_) + (skoff >> 1),              \
          SMb + 16384 + (buf_)*8192 + (t << 4) + 4096);                        \
  }

  bf16x8 qf[2];
  {
    const u16* qr = Qb + (size_t)(q0 + qrow) * 64;
    qf[0] = g8(qr + lg * 8);
    qf[1] = g8(qr + 32 + lg * 8);
  }

  int swzq = (lr & 7) << 4;

  // ================= pass 0: rowsums (KC=128) =================
  float rsum = 0.f;
  {
    STAGE_K2(0, 0);
    u32x4 mq = *(const u32x4*)(Mrow);
    u32x4 mqn;
    for (int tt = 0; tt < 16; ++tt) {
      int cur = tt & 1;
      if (tt < 15) {
        STAGE_K2((tt + 1) * 128, cur ^ 1);
        mqn = *(const u32x4*)(Mrow + ((tt + 1) << 2));
        WAITV(5);
      } else {
        WAITV(0);
      }
      SCHED0();
      BAR();
      const u16* Kc = (const u16*)(SMb + cur * 16384);
#pragma unroll
      for (int nf = 0; nf < 8; ++nf) {
        int krow = nf * 16 + lr;
        int base = krow << 7, swz = (krow & 7) << 4;
        f32x4 sc = {};
        __builtin_amdgcn_s_setprio(1);
        sc = __builtin_amdgcn_mfma_f32_16x16x32_bf16(
            lds8(Kc, base + ((lg << 4) ^ swz)), qf[0], sc, 0, 0, 0);
        sc = __builtin_amdgcn_mfma_f32_16x16x32_bf16(
            lds8(Kc, base + ((64 + (lg << 4)) ^ swz)), qf[1], sc, 0, 0, 0);
        __builtin_amdgcn_s_setprio(0);
        u32 mb = mq[nf >> 1] >> (((nf & 1) << 4) + (lg << 2));
#pragma unroll
        for (int r = 0; r < 4; ++r)
          rsum += ((mb >> r) & 1) ? 0.f : __builtin_amdgcn_exp2f(sc[r]);
      }
      mq = mqn;
      BAR();
    }
  }
  float inv;
  {
    float s = rsum;
    s += __shfl_xor(s, 16);
    s += __shfl_xor(s, 32);
    inv = 1.0f / s;
  }

  // ================= pass 1: write attention + P.V (KC=64) ============
  float* abase = attn + ((size_t)bh * Ss + q0 + w * 16) * Ss;  // wave's 16 rows
  int rsub = l >> 4;
  int kch = (l & 15);
  f32x4 ctx[4] = {};
  {
    STAGE_K(0, 0);
    STAGE_V(0, 0);
    u32x2 mq = *(const u32x2*)(Mrow);
    u32x2 mqn;
    for (int tt = 0; tt < 32; ++tt) {
      int cur = tt & 1;
      if (tt == 0) {
        STAGE_K(64, 1);
        STAGE_V(64, 1);
        mqn = *(const u32x2*)(Mrow + 2);
        WAITV(5);
      } else if (tt < 31) {
        STAGE_K((tt + 1) * 64, cur ^ 1);
        STAGE_V((tt + 1) * 64, cur ^ 1);
        mqn = *(const u32x2*)(Mrow + ((tt + 1) << 1));
        WAITV(9);
      } else {
        WAITV(4);
      }
      SCHED0();
      BAR();
      const u16* Kc = (const u16*)(SMb + cur * 8192);
      const u16* Vc = (const u16*)(SMb + 16384 + cur * 8192);
      int kc = tt * 64;
#pragma unroll
      for (int nf = 0; nf < 4; ++nf) {
        int krow = nf * 16 + lr;
        int base = krow << 7, swz = (krow & 7) << 4;
        f32x4 sc = {};
        __builtin_amdgcn_s_setprio(1);
        sc = __builtin_amdgcn_mfma_f32_16x16x32_bf16(
            lds8(Kc, base + ((lg << 4) ^ swz)), qf[0], sc, 0, 0, 0);
        sc = __builtin_amdgcn_mfma_f32_16x16x32_bf16(
            lds8(Kc, base + ((64 + (lg << 4)) ^ swz)), qf[1], sc, 0, 0, 0);
        __builtin_amdgcn_s_setprio(0);
        u32 mb = mq[nf >> 1] >> (((nf & 1) << 4) + (lg << 2));
        f32x4 p4;
#pragma unroll
        for (int r = 0; r < 4; ++r)
          p4[r] = (((mb >> r) & 1) ? 0.f : __builtin_amdgcn_exp2f(sc[r])) * inv;
        bf16x4 pb;
#pragma unroll
        for (int r = 0; r < 4; ++r) pb[r] = (__bf16)p4[r];
        *(bf16x4*)((char*)Pl + (qrow << 7) + (((nf << 5) + (lg << 3)) ^ swzq)) = pb;
      }
      // redistribute: wave-private rows, 4 iterations of 4 rows x 256B
#pragma unroll
      for (int rb = 0; rb < 4; ++rb) {
        int rrow = rb * 4 + rsub;
        int R = w * 16 + rrow;
        bf16x4 pv4 = lds4(Pl, (R << 7) + ((kch << 3) ^ ((R & 7) << 4)));
        f32x4 o4;
#pragma unroll
        for (int r = 0; r < 4; ++r) o4[r] = (float)pv4[r];
        __builtin_nontemporal_store(
            o4, (f32x4*)(abase + (size_t)rrow * Ss + kc + kch * 4));
      }
      // P.V over this 64-k tile
      __builtin_amdgcn_s_setprio(1);
#pragma unroll
      for (int ks = 0; ks < 2; ++ks) {
        bf16x8 pf = lds8(Pl, (qrow << 7) + (((ks << 6) + (lg << 4)) ^ swzq));
#pragma unroll
        for (int nfo = 0; nfo < 4; ++nfo) {
          int vr = nfo * 16 + lr;
          bf16x8 vf = lds8(Vc,
                           (vr << 7) + (((ks << 6) + (lg << 4)) ^ ((vr & 7) << 4)));
          ctx[nfo] = __builtin_amdgcn_mfma_f32_16x16x32_bf16(pf, vf, ctx[nfo], 0, 0, 0);
        }
      }
      __builtin_amdgcn_s_setprio(0);
      mq = mqn;
      BAR();
    }
  }
#undef STAGE_K2
#undef STAGE_K
#undef STAGE_V

  // coalesced Ctx write via LDS (arena free after final barrier; wave-private)
  {
    u16* Cl = (u16*)SMb + w * 1024;  // 16 rows x 64 u16
#pragma unroll
    for (int nfo = 0; nfo < 4; ++nfo)
#pragma unroll
      for (int r = 0; r < 4; ++r)
        Cl[(lg * 4 + r) * 64 + nfo * 16 + lr] = bfbits(ctx[nfo][r]);
#pragma unroll
    for (int i = 0; i < 2; ++i) {
      int row = (l >> 3) + (i << 3);
      u16x8 cv = *(const u16x8*)(Cl + row * 64 + (l & 7) * 8);
      *(u16x8*)&Ctx[((size_t)b * Ss + q0 + w * 16 + row) * 1024 + h * 64 +
                    (l & 7) * 8] = cv;
    }
  }
}

// ---------------- K3: output projection + bias + residual (XCD swizzle) ----
__global__ __launch_bounds__(256) void gemm_out(const u16* __restrict__ Ctx,
                                                const u16* __restrict__ Wot,
                                                const float* __restrict__ bo,
                                                const float* __restrict__ resid,
                                                float* __restrict__ preLN) {
  __shared__ __attribute__((aligned(16))) u16 Al[2][128 * 32];
  __shared__ __attribute__((aligned(16))) u16 Bl[2][128 * 32];

  int t = threadIdx.x, w = t >> 6, l = t & 63, lg = l >> 4, lr = l & 15;
  int n_ = blockIdx.x;
  int cx = n_ & 7, slot = n_ >> 3;
  int m0 = (((slot >> 3) << 3) | cx) * 128;
  int n0 = (slot & 7) * 128;
  int wm = (w >> 1) * 64, wn = (w & 1) * 64;

  f32x4 acc[4][4] = {};

#define STAGE_AB(kt_, buf_)                                                    \
  {                                                                            \
    _Pragma("unroll") for (int i = 0; i < 2; ++i) {                            \
      int c = t + i * 256;                                                     \
      int d = c << 4;                                                          \
      int row = d >> 6, off = d & 63;                                          \
      int soff = off ^ ((row & 3) << 4);                                       \
      gll16(Ctx + (size_t)(m0 + row) * 1024 + (kt_) + (soff >> 1),             \
            (char*)Al[buf_] + d);                                              \
      gll16(Wot + (size_t)(n0 + row) * 1024 + (kt_) + (soff >> 1),             \
            (char*)Bl[buf_] + d);                                              \
    }                                                                          \
  }

  STAGE_AB(0, 0);

  for (int tt = 0; tt < 32; ++tt) {
    int cur = tt & 1;
    if (tt < 31) {
      STAGE_AB((tt + 1) * 32, cur ^ 1);
      WAITV(4);
    } else {
      WAITV(0);
    }
    SCHED0();
    BAR();
    bf16x8 af[4], bfr[4];
#pragma unroll
    for (int mf = 0; mf < 4; ++mf) {
      int row = wm + mf * 16 + lr;
      af[mf] = lds8(Al[cur], (row << 6) + ((lg ^ (row & 3)) << 4));
    }
#pragma unroll
    for (int nf = 0; nf < 4; ++nf) {
      int row = wn + nf * 16 + lr;
      bfr[nf] = lds8(Bl[cur], (row << 6) + ((lg ^ (row & 3)) << 4));
    }
#pragma unroll
    for (int mf = 0; mf < 4; ++mf)
#pragma unroll
      for (int nf = 0; nf < 4; ++nf)
        acc[mf][nf] = __builtin_amdgcn_mfma_f32_16x16x32_bf16(af[mf], bfr[nf], acc[mf][nf], 0, 0, 0);
    BAR();
  }
#undef STAGE_AB

#pragma unroll
  for (int mf = 0; mf < 4; ++mf)
#pragma unroll
    for (int nf = 0; nf < 4; ++nf)
#pragma unroll
      for (int r = 0; r < 4; ++r) {
        int m = m0 + wm + mf * 16 + lg * 4 + r;
        int n = n0 + wn + nf * 16 + lr;
        float v = acc[mf][nf][r] + bo[n] + resid[(size_t)m * 1024 + n];
        preLN[(size_t)m * 1024 + n] = v;
      }
}

// ---------------- K4: LayerNorm (1 wave per row, 4 rows per block) ---------
__global__ __launch_bounds__(256) void layernorm(const float* __restrict__ x,
                                                 const float* __restrict__ gamma,
                                                 const float* __restrict__ beta,
                                                 float* __restrict__ out) {
  int t = threadIdx.x;
  int w = t >> 6, l = t & 63;
  int row = blockIdx.x * 4 + w;
  const float* xr = x + (size_t)row * 1024;
  float4 v[4];
  float s = 0.f, s2 = 0.f;
#pragma unroll
  for (int c = 0; c < 4; ++c) {
    v[c] = *(const float4*)(xr + c * 256 + l * 4);
    s += v[c].x + v[c].y + v[c].z + v[c].w;
    s2 += v[c].x * v[c].x + v[c].y * v[c].y + v[c].z * v[c].z + v[c].w * v[c].w;
  }
#pragma unroll
  for (int m = 1; m < 64; m <<= 1) {
    s += __shfl_xor(s, m);
    s2 += __shfl_xor(s2, m);
  }
  float mu = s * (1.0f / 1024.0f);
  float var = s2 * (1.0f / 1024.0f) - mu * mu;
  float rs = rsqrtf(var + 1e-5f);
  float* orow = out + (size_t)row * 1024;
#pragma unroll
  for (int c = 0; c < 4; ++c) {
    float4 g = *(const float4*)(gamma + c * 256 + l * 4);
    float4 bb = *(const float4*)(beta + c * 256 + l * 4);
    float4 o;
    o.x = (v[c].x - mu) * rs * g.x + bb.x;
    o.y = (v[c].y - mu) * rs * g.y + bb.y;
    o.z = (v[c].z - mu) * rs * g.z + bb.z;
    o.w = (v[c].w - mu) * rs * g.w + bb.w;
    *(float4*)(orow + c * 256 + l * 4) = o;
  }
}

// ---------------- launch ----------------
extern "C" void kernel_launch(void* const* d_in, const int* in_sizes, int n_in,
                              void* d_out, int out_size, void* d_ws, size_t ws_size,
                              hipStream_t stream) {
  const float* Xq = (const float*)d_in[0];
  const float* Xk = (const float*)d_in[1];
  const float* Xv = (const float*)d_in[2];
  const int* Mask = (const int*)d_in[3];
  const float* Wq = (const float*)d_in[4];
  const float* bq = (const float*)d_in[5];
  const float* Wk = (const float*)d_in[6];
  const float* bk = (const float*)d_in[7];
  const float* Wv = (const float*)d_in[8];
  const float* bv = (const float*)d_in[9];
  const float* Wo = (const float*)d_in[10];
  const float* bo = (const float*)d_in[11];
  const float* gamma = (const float*)d_in[12];
  const float* beta = (const float*)d_in[13];

  char* ws = (char*)d_ws;
  u16* Xbf   = (u16*)(ws + 0);            // 48 MiB (aliased by preLN later)
  u16* Wt    = (u16*)(ws + 50331648);     // 8 MiB
  u16* Qs    = (u16*)(ws + 58720256);     // 16 MiB (Q), then K contiguous
  u16* Vt    = (u16*)(ws + 92274688);     // 16 MiB [bh][dv][s]
  u32* Mbits = (u32*)(ws + 109051904);    // 2 MiB
  u16* Ctx   = (u16*)(ws + 111149056);    // 16 MiB
  float* preLN = (float*)(ws + 0);        // 32 MiB, aliases Xbf (dead by then)

  u16* Ks = Qs + 8192ull * 1024;

  float* outp = (float*)d_out;
  float* attn = outp + 8388608ull;

  (void)in_sizes; (void)n_in; (void)out_size; (void)ws_size;

  convert_x<<<dim3(4096, 3), 256, 0, stream>>>(Xq, Xk, Xv, Xbf);
  conv_w<<<dim3(16, 16, 4), 256, 0, stream>>>(Wq, Wk, Wv, Wo, Wt);
  pack_mask<<<32768, 256, 0, stream>>>(Mask, Mbits);
  gemm_qkv<<<dim3(512, 1, 3), 256, 0, stream>>>(Xbf, Wt, bq, bk, bv, Qs, Vt);
  attn_kernel<<<2048, 256, 0, stream>>>(Qs, Ks, Vt, Mbits, attn, Ctx);
  gemm_out<<<512, 256, 0, stream>>>(Ctx, Wt + 3ull * 1048576, bo, Xq, preLN);
  layernorm<<<2048, 256, 0, stream>>>(preLN, gamma, beta, outp);
}

// Round 12
// 379.958 us; speedup vs baseline: 1.3279x; 1.0277x over previous
//
#include <hip/hip_runtime.h>

typedef unsigned short u16;
typedef unsigned int u32;
typedef __bf16 bf16x8 __attribute__((ext_vector_type(8)));
typedef __bf16 bf16x4 __attribute__((ext_vector_type(4)));
typedef u16 u16x8 __attribute__((ext_vector_type(8)));
typedef u32 u32x2 __attribute__((ext_vector_type(2)));
typedef u32 u32x4 __attribute__((ext_vector_type(4)));
typedef float f32x4 __attribute__((ext_vector_type(4)));

#define Ss 2048
#define Hh 16

#define WAITV(n) asm volatile("s_waitcnt vmcnt(" #n ")" ::: "memory")
#define BAR() __builtin_amdgcn_s_barrier()
#define SCHED0() __builtin_amdgcn_sched_barrier(0)

__device__ __forceinline__ void gll16(const void* g, void* l) {
  __builtin_amdgcn_global_load_lds((const __attribute__((address_space(1))) void*)g,
                                   (__attribute__((address_space(3))) void*)l, 16, 0, 0);
}

__device__ __forceinline__ bf16x8 lds8(const u16* base, int byteoff) {
  return __builtin_bit_cast(bf16x8, *(const u16x8*)((const char*)base + byteoff));
}
__device__ __forceinline__ bf16x4 lds4(const u16* base, int byteoff) {
  return __builtin_bit_cast(bf16x4, *(const unsigned long long*)((const char*)base + byteoff));
}
__device__ __forceinline__ bf16x8 g8(const u16* p) {
  return __builtin_bit_cast(bf16x8, *(const u16x8*)p);
}
__device__ __forceinline__ u16 bfbits(float f) {
  return __builtin_bit_cast(u16, (__bf16)f);
}

// ---------------- K0: merged prep (convert X, transpose W, pack mask) ------
// blocks [0,12288): convert_x; [12288,13312): conv_w; [13312,46080): pack_mask
__global__ __launch_bounds__(256) void prep(const float* __restrict__ xq,
                                            const float* __restrict__ xk,
                                            const float* __restrict__ xv,
                                            const float* __restrict__ wq,
                                            const float* __restrict__ wk,
                                            const float* __restrict__ wv,
                                            const float* __restrict__ wo,
                                            const int* __restrict__ mask,
                                            u16* __restrict__ Xbf,
                                            u16* __restrict__ wt,
                                            u32* __restrict__ bits) {
  __shared__ float tile[64][65];
  int bid = blockIdx.x;
  int t = threadIdx.x;
  if (bid < 12288) {
    int z = bid >> 12;
    int sub = bid & 4095;
    const float* src = (z == 0) ? xq : ((z == 1) ? xk : xv);
    u16* d = Xbf + (size_t)z * (8192ull * 1024);
    size_t i = ((size_t)sub * 256 + t) * 8;
    f32x4 v0, v1;
    if (z == 0) {  // Xq re-read later as residual: keep cacheable
      v0 = *(const f32x4*)(src + i);
      v1 = *(const f32x4*)(src + i + 4);
    } else {       // read-once: non-temporal
      v0 = __builtin_nontemporal_load((const f32x4*)(src + i));
      v1 = __builtin_nontemporal_load((const f32x4*)(src + i + 4));
    }
    bf16x8 o;
    o[0] = (__bf16)v0[0]; o[1] = (__bf16)v0[1]; o[2] = (__bf16)v0[2]; o[3] = (__bf16)v0[3];
    o[4] = (__bf16)v1[0]; o[5] = (__bf16)v1[1]; o[6] = (__bf16)v1[2]; o[7] = (__bf16)v1[3];
    *(bf16x8*)(d + i) = o;
  } else if (bid < 13312) {
    int idx = bid - 12288;
    int z = idx >> 8;
    const float* W = (z == 0) ? wq : (z == 1) ? wk : (z == 2) ? wv : wo;
    u16* O = wt + (size_t)z * (1024ull * 1024);
    int tk = (idx & 15) * 64, tn = ((idx >> 4) & 15) * 64;
#pragma unroll
    for (int p = 0; p < 4; ++p) {
      int id2 = p * 256 + t;
      int r = id2 >> 4, c4 = (id2 & 15) << 2;
      f32x4 v = *(const f32x4*)(W + (size_t)(tk + r) * 1024 + tn + c4);
      tile[r][c4 + 0] = v[0]; tile[r][c4 + 1] = v[1];
      tile[r][c4 + 2] = v[2]; tile[r][c4 + 3] = v[3];
    }
    __syncthreads();
#pragma unroll
    for (int p = 0; p < 4; ++p) {
      int id2 = p * 256 + t;
      int n = id2 >> 4, k4 = (id2 & 15) << 2;
      bf16x4 o;
      o[0] = (__bf16)tile[k4 + 0][n]; o[1] = (__bf16)tile[k4 + 1][n];
      o[2] = (__bf16)tile[k4 + 2][n]; o[3] = (__bf16)tile[k4 + 3][n];
      *(bf16x4*)(O + (size_t)(tn + n) * 1024 + tk + k4) = o;
    }
  } else {
    size_t base = (size_t)(bid - 13312) * 512;
    int w = t >> 6, lane = t & 63;
    bool v0 = (__builtin_nontemporal_load(&mask[base + t]) != 0);
    bool v1 = (__builtin_nontemporal_load(&mask[base + 256 + t]) != 0);
    unsigned long long b0 = __ballot(v0);
    unsigned long long b1 = __ballot(v1);
    size_t wbase = (base >> 5) + (w << 1);
    if (lane == 0) {
      bits[wbase] = (u32)b0;
      bits[wbase + 8] = (u32)b1;
    } else if (lane == 32) {
      bits[wbase + 1] = (u32)(b0 >> 32);
      bits[wbase + 9] = (u32)(b1 >> 32);
    }
  }
}

// ---------------- K1: QKV projection GEMM (counted-vmcnt + XCD swizzle) ----
__global__ __launch_bounds__(256) void gemm_qkv(const u16* __restrict__ Xbf,
                                                const u16* __restrict__ Wt,
                                                const float* __restrict__ bq,
                                                const float* __restrict__ bk,
                                                const float* __restrict__ bv,
                                                u16* __restrict__ OutQK,
                                                u16* __restrict__ Vt) {
  int z = blockIdx.z;
  const u16* A = Xbf + (size_t)z * (8192ull * 1024);
  const u16* Bw = Wt + (size_t)z * (1024ull * 1024);
  const float* bias = (z == 0) ? bq : ((z == 1) ? bk : bv);
  u16* O = OutQK + (size_t)z * (8192ull * 1024);
  float scale = (z == 0) ? (0.125f * 1.4426950408889634f) : 1.0f;

  __shared__ __attribute__((aligned(16))) u16 SM[16384];

  int t = threadIdx.x, w = t >> 6, l = t & 63, lg = l >> 4, lr = l & 15;
  int n_ = blockIdx.x;
  int cx = n_ & 7, slot = n_ >> 3;
  int m0 = (((slot >> 3) << 3) | cx) * 128;
  int n0 = (slot & 7) * 128;
  int wm = (w >> 1) * 64, wn = (w & 1) * 64;

  f32x4 acc[4][4] = {};

#define STAGE_AB(kt_, buf_)                                                    \
  {                                                                            \
    _Pragma("unroll") for (int i = 0; i < 2; ++i) {                            \
      int c = t + i * 256;                                                     \
      int d = c << 4;                                                          \
      int row = d >> 6, off = d & 63;                                          \
      int soff = off ^ ((row & 3) << 4);                                       \
      gll16(A + (size_t)(m0 + row) * 1024 + (kt_) + (soff >> 1),               \
            (char*)SM + (buf_)*8192 + d);                                      \
      gll16(Bw + (size_t)(n0 + row) * 1024 + (kt_) + (soff >> 1),              \
            (char*)SM + 16384 + (buf_)*8192 + d);                              \
    }                                                                          \
  }

  STAGE_AB(0, 0);

  for (int tt = 0; tt < 32; ++tt) {
    int cur = tt & 1;
    if (tt < 31) {
      STAGE_AB((tt + 1) * 32, cur ^ 1);
      WAITV(4);
    } else {
      WAITV(0);
    }
    SCHED0();
    BAR();
    const u16* Ac = SM + cur * 4096;
    const u16* Bc = SM + 8192 + cur * 4096;
    bf16x8 af[4], bfr[4];
#pragma unroll
    for (int mf = 0; mf < 4; ++mf) {
      int row = wm + mf * 16 + lr;
      af[mf] = lds8(Ac, (row << 6) + ((lg ^ (row & 3)) << 4));
    }
#pragma unroll
    for (int nf = 0; nf < 4; ++nf) {
      int row = wn + nf * 16 + lr;
      bfr[nf] = lds8(Bc, (row << 6) + ((lg ^ (row & 3)) << 4));
    }
#pragma unroll
    for (int mf = 0; mf < 4; ++mf)
#pragma unroll
      for (int nf = 0; nf < 4; ++nf)
        acc[mf][nf] = __builtin_amdgcn_mfma_f32_16x16x32_bf16(af[mf], bfr[nf], acc[mf][nf], 0, 0, 0);
    BAR();
  }
#undef STAGE_AB

  if (z == 2) {
#pragma unroll
    for (int mf = 0; mf < 4; ++mf)
#pragma unroll
      for (int nf = 0; nf < 4; ++nf) {
        int mloc = wm + mf * 16 + lg * 4;
        int nloc = wn + nf * 16 + lr;
        bf16x4 ov;
        int n = n0 + nloc;
#pragma unroll
        for (int r = 0; r < 4; ++r) ov[r] = (__bf16)(acc[mf][nf][r] + bias[n]);
        *(bf16x4*)&SM[nloc * 128 + (mloc ^ ((nloc & 7) << 3))] = ov;
      }
    BAR();
    int b_ = m0 >> 11, s0_ = m0 & 2047;
#pragma unroll
    for (int i = 0; i < 8; ++i) {
      int idx = i * 256 + t;
      int nloc = idx >> 4, c = idx & 15;
      u16x8 val = *(const u16x8*)&SM[nloc * 128 + (((c ^ (nloc & 7)) << 3))];
      int n = n0 + nloc, hh = n >> 6, dd = n & 63;
      *(u16x8*)&Vt[(((size_t)(b_ * 16 + hh)) * 64 + dd) * 2048 + s0_ + c * 8] = val;
    }
  } else {
#pragma unroll
    for (int mf = 0; mf < 4; ++mf)
#pragma unroll
      for (int nf = 0; nf < 4; ++nf)
#pragma unroll
        for (int r = 0; r < 4; ++r) {
          int row = wm + mf * 16 + lg * 4 + r;
          int col = wn + nf * 16 + lr;
          float v = (acc[mf][nf][r] + bias[n0 + col]) * scale;
          SM[row * 128 + (col ^ ((row & 7) << 3))] = bfbits(v);
        }
    BAR();
    int b_ = m0 >> 11, s0_ = m0 & 2047;
#pragma unroll
    for (int i = 0; i < 8; ++i) {
      int idx = i * 256 + t;
      int row = idx >> 4, c = idx & 15;
      u16x8 val = *(const u16x8*)&SM[row * 128 + (((c ^ (row & 7)) << 3))];
      int n = n0 + c * 8, hh = n >> 6, dd = n & 63;
      *(u16x8*)&O[(((size_t)(b_ * 16 + hh)) * 2048 + s0_ + row) * 64 + dd] = val;
    }
  }
}

// ---------------- K2: staged fused attention (byte-identical to R10) -------
__global__ __launch_bounds__(256, 4) void attn_kernel(const u16* __restrict__ Qs,
                                                      const u16* __restrict__ Ks,
                                                      const u16* __restrict__ Vt,
                                                      const u32* __restrict__ Mbits,
                                                      float* __restrict__ attn,
                                                      u16* __restrict__ Ctx) {
  int bid = blockIdx.x;
  int xcd = bid & 7, j = bid >> 3;
  int bh = xcd * 8 + (j >> 5);
  int q0 = (j & 31) * 64;
  int b = bh >> 4, h = bh & 15;
  int t = threadIdx.x;
  int w = t >> 6, l = t & 63, lg = l >> 4, lr = l & 15;

  const u16* Qb = Qs + (size_t)bh * (Ss * 64);
  const u16* Kb = Ks + (size_t)bh * (Ss * 64);
  const u16* Vb = Vt + (size_t)bh * (64 * Ss);
  int qrow = w * 16 + lr;
  const u32* Mrow = Mbits + ((size_t)b * Ss + q0 + qrow) * 64;

  __shared__ __attribute__((aligned(16))) char SMb[40960];
  u16* Pl = (u16*)(SMb + 32768);

  int srow = t >> 3;
  int skoff = (((t & 7) << 4) ^ ((srow & 7) << 4));

#define STAGE_K2(kc_, buf_)                                                    \
  {                                                                            \
    _Pragma("unroll") for (int i = 0; i < 4; ++i)                              \
        gll16(Kb + (size_t)((kc_) + srow + 32 * i) * 64 + (skoff >> 1),        \
              SMb + (buf_)*16384 + i * 4096 + (t << 4));                       \
  }
#define STAGE_K(kc_, buf_)                                                     \
  {                                                                            \
    gll16(Kb + (size_t)((kc_) + srow) * 64 + (skoff >> 1),                     \
          SMb + (buf_)*8192 + (t << 4));                                       \
    gll16(Kb + (size_t)((kc_) + srow + 32) * 64 + (skoff >> 1),                \
          SMb + (buf_)*8192 + (t << 4) + 4096);                                \
  }
#define STAGE_V(kc_, buf_)                                                     \
  {                                                                            \
    gll16(Vb + (size_t)srow * 2048 + (kc_) + (skoff >> 1),                     \
          SMb + 16384 + (buf_)*8192 + (t << 4));                               \
    gll16(Vb + (size_t)(srow + 32) * 2048 + (kc_) + (skoff >> 1),              \
          SMb + 16384 + (buf_)*8192 + (t << 4) + 4096);                        \
  }

  bf16x8 qf[2];
  {
    const u16* qr = Qb + (size_t)(q0 + qrow) * 64;
    qf[0] = g8(qr + lg * 8);
    qf[1] = g8(qr + 32 + lg * 8);
  }

  int swzq = (lr & 7) << 4;

  float rsum = 0.f;
  {
    STAGE_K2(0, 0);
    u32x4 mq = *(const u32x4*)(Mrow);
    u32x4 mqn;
    for (int tt = 0; tt < 16; ++tt) {
      int cur = tt & 1;
      if (tt < 15) {
        STAGE_K2((tt + 1) * 128, cur ^ 1);
        mqn = *(const u32x4*)(Mrow + ((tt + 1) << 2));
        WAITV(5);
      } else {
        WAITV(0);
      }
      SCHED0();
      BAR();
      const u16* Kc = (const u16*)(SMb + cur * 16384);
#pragma unroll
      for (int nf = 0; nf < 8; ++nf) {
        int krow = nf * 16 + lr;
        int base = krow << 7, swz = (krow & 7) << 4;
        f32x4 sc = {};
        __builtin_amdgcn_s_setprio(1);
        sc = __builtin_amdgcn_mfma_f32_16x16x32_bf16(
            lds8(Kc, base + ((lg << 4) ^ swz)), qf[0], sc, 0, 0, 0);
        sc = __builtin_amdgcn_mfma_f32_16x16x32_bf16(
            lds8(Kc, base + ((64 + (lg << 4)) ^ swz)), qf[1], sc, 0, 0, 0);
        __builtin_amdgcn_s_setprio(0);
        u32 mb = mq[nf >> 1] >> (((nf & 1) << 4) + (lg << 2));
#pragma unroll
        for (int r = 0; r < 4; ++r)
          rsum += ((mb >> r) & 1) ? 0.f : __builtin_amdgcn_exp2f(sc[r]);
      }
      mq = mqn;
      BAR();
    }
  }
  float inv;
  {
    float s = rsum;
    s += __shfl_xor(s, 16);
    s += __shfl_xor(s, 32);
    inv = 1.0f / s;
  }

  float* abase = attn + ((size_t)bh * Ss + q0 + w * 16) * Ss;
  int rsub = l >> 4;
  int kch = (l & 15);
  f32x4 ctx[4] = {};
  {
    STAGE_K(0, 0);
    STAGE_V(0, 0);
    u32x2 mq = *(const u32x2*)(Mrow);
    u32x2 mqn;
    for (int tt = 0; tt < 32; ++tt) {
      int cur = tt & 1;
      if (tt == 0) {
        STAGE_K(64, 1);
        STAGE_V(64, 1);
        mqn = *(const u32x2*)(Mrow + 2);
        WAITV(5);
      } else if (tt < 31) {
        STAGE_K((tt + 1) * 64, cur ^ 1);
        STAGE_V((tt + 1) * 64, cur ^ 1);
        mqn = *(const u32x2*)(Mrow + ((tt + 1) << 1));
        WAITV(9);
      } else {
        WAITV(4);
      }
      SCHED0();
      BAR();
      const u16* Kc = (const u16*)(SMb + cur * 8192);
      const u16* Vc = (const u16*)(SMb + 16384 + cur * 8192);
      int kc = tt * 64;
#pragma unroll
      for (int nf = 0; nf < 4; ++nf) {
        int krow = nf * 16 + lr;
        int base = krow << 7, swz = (krow & 7) << 4;
        f32x4 sc = {};
        __builtin_amdgcn_s_setprio(1);
        sc = __builtin_amdgcn_mfma_f32_16x16x32_bf16(
            lds8(Kc, base + ((lg << 4) ^ swz)), qf[0], sc, 0, 0, 0);
        sc = __builtin_amdgcn_mfma_f32_16x16x32_bf16(
            lds8(Kc, base + ((64 + (lg << 4)) ^ swz)), qf[1], sc, 0, 0, 0);
        __builtin_amdgcn_s_setprio(0);
        u32 mb = mq[nf >> 1] >> (((nf & 1) << 4) + (lg << 2));
        f32x4 p4;
#pragma unroll
        for (int r = 0; r < 4; ++r)
          p4[r] = (((mb >> r) & 1) ? 0.f : __builtin_amdgcn_exp2f(sc[r])) * inv;
        bf16x4 pb;
#pragma unroll
        for (int r = 0; r < 4; ++r) pb[r] = (__bf16)p4[r];
        *(bf16x4*)((char*)Pl + (qrow << 7) + (((nf << 5) + (lg << 3)) ^ swzq)) = pb;
      }
#pragma unroll
      for (int rb = 0; rb < 4; ++rb) {
        int rrow = rb * 4 + rsub;
        int R = w * 16 + rrow;
        bf16x4 pv4 = lds4(Pl, (R << 7) + ((kch << 3) ^ ((R & 7) << 4)));
        f32x4 o4;
#pragma unroll
        for (int r = 0; r < 4; ++r) o4[r] = (float)pv4[r];
        __builtin_nontemporal_store(
            o4, (f32x4*)(abase + (size_t)rrow * Ss + kc + kch * 4));
      }
      __builtin_amdgcn_s_setprio(1);
#pragma unroll
      for (int ks = 0; ks < 2; ++ks) {
        bf16x8 pf = lds8(Pl, (qrow << 7) + (((ks << 6) + (lg << 4)) ^ swzq));
#pragma unroll
        for (int nfo = 0; nfo < 4; ++nfo) {
          int vr = nfo * 16 + lr;
          bf16x8 vf = lds8(Vc,
                           (vr << 7) + (((ks << 6) + (lg << 4)) ^ ((vr & 7) << 4)));
          ctx[nfo] = __builtin_amdgcn_mfma_f32_16x16x32_bf16(pf, vf, ctx[nfo], 0, 0, 0);
        }
      }
      __builtin_amdgcn_s_setprio(0);
      mq = mqn;
      BAR();
    }
  }
#undef STAGE_K2
#undef STAGE_K
#undef STAGE_V

  {
    u16* Cl = (u16*)SMb + w * 1024;
#pragma unroll
    for (int nfo = 0; nfo < 4; ++nfo)
#pragma unroll
      for (int r = 0; r < 4; ++r)
        Cl[(lg * 4 + r) * 64 + nfo * 16 + lr] = bfbits(ctx[nfo][r]);
#pragma unroll
    for (int i = 0; i < 2; ++i) {
      int row = (l >> 3) + (i << 3);
      u16x8 cv = *(const u16x8*)(Cl + row * 64 + (l & 7) * 8);
      *(u16x8*)&Ctx[((size_t)b * Ss + q0 + w * 16 + row) * 1024 + h * 64 +
                    (l & 7) * 8] = cv;
    }
  }
}

// ---------------- K3: output projection + bias + residual -> bf16 preLN ----
__global__ __launch_bounds__(256) void gemm_out(const u16* __restrict__ Ctx,
                                                const u16* __restrict__ Wot,
                                                const float* __restrict__ bo,
                                                const float* __restrict__ resid,
                                                u16* __restrict__ preLN16) {
  __shared__ __attribute__((aligned(16))) u16 SM[16384];

  int t = threadIdx.x, w = t >> 6, l = t & 63, lg = l >> 4, lr = l & 15;
  int n_ = blockIdx.x;
  int cx = n_ & 7, slot = n_ >> 3;
  int m0 = (((slot >> 3) << 3) | cx) * 128;
  int n0 = (slot & 7) * 128;
  int wm = (w >> 1) * 64, wn = (w & 1) * 64;

  f32x4 acc[4][4] = {};

#define STAGE_AB(kt_, buf_)                                                    \
  {                                                                            \
    _Pragma("unroll") for (int i = 0; i < 2; ++i) {                            \
      int c = t + i * 256;                                                     \
      int d = c << 4;                                                          \
      int row = d >> 6, off = d & 63;                                          \
      int soff = off ^ ((row & 3) << 4);                                       \
      gll16(Ctx + (size_t)(m0 + row) * 1024 + (kt_) + (soff >> 1),             \
            (char*)SM + (buf_)*8192 + d);                                      \
      gll16(Wot + (size_t)(n0 + row) * 1024 + (kt_) + (soff >> 1),             \
            (char*)SM + 16384 + (buf_)*8192 + d);                              \
    }                                                                          \
  }

  STAGE_AB(0, 0);

  for (int tt = 0; tt < 32; ++tt) {
    int cur = tt & 1;
    if (tt < 31) {
      STAGE_AB((tt + 1) * 32, cur ^ 1);
      WAITV(4);
    } else {
      WAITV(0);
    }
    SCHED0();
    BAR();
    const u16* Ac = SM + cur * 4096;
    const u16* Bc = SM + 8192 + cur * 4096;
    bf16x8 af[4], bfr[4];
#pragma unroll
    for (int mf = 0; mf < 4; ++mf) {
      int row = wm + mf * 16 + lr;
      af[mf] = lds8(Ac, (row << 6) + ((lg ^ (row & 3)) << 4));
    }
#pragma unroll
    for (int nf = 0; nf < 4; ++nf) {
      int row = wn + nf * 16 + lr;
      bfr[nf] = lds8(Bc, (row << 6) + ((lg ^ (row & 3)) << 4));
    }
#pragma unroll
    for (int mf = 0; mf < 4; ++mf)
#pragma unroll
      for (int nf = 0; nf < 4; ++nf)
        acc[mf][nf] = __builtin_amdgcn_mfma_f32_16x16x32_bf16(af[mf], bfr[nf], acc[mf][nf], 0, 0, 0);
    BAR();
  }
#undef STAGE_AB

  // epilogue: stage bf16(acc+bias) in SM, then full-line stores with residual
#pragma unroll
  for (int mf = 0; mf < 4; ++mf)
#pragma unroll
    for (int nf = 0; nf < 4; ++nf)
#pragma unroll
      for (int r = 0; r < 4; ++r) {
        int row = wm + mf * 16 + lg * 4 + r;
        int col = wn + nf * 16 + lr;
        float v = acc[mf][nf][r] + bo[n0 + col];
        SM[row * 128 + (col ^ ((row & 7) << 3))] = bfbits(v);
      }
  BAR();
#pragma unroll
  for (int i = 0; i < 8; ++i) {
    int idx = i * 256 + t;
    int row = idx >> 4, c = idx & 15;
    u16x8 val = *(const u16x8*)&SM[row * 128 + (((c ^ (row & 7)) << 3))];
    bf16x8 vb = __builtin_bit_cast(bf16x8, val);
    const float* rr = resid + (size_t)(m0 + row) * 1024 + n0 + c * 8;
    f32x4 f0 = *(const f32x4*)rr;
    f32x4 f1 = *(const f32x4*)(rr + 4);
    bf16x8 o;
    o[0] = (__bf16)((float)vb[0] + f0[0]);
    o[1] = (__bf16)((float)vb[1] + f0[1]);
    o[2] = (__bf16)((float)vb[2] + f0[2]);
    o[3] = (__bf16)((float)vb[3] + f0[3]);
    o[4] = (__bf16)((float)vb[4] + f1[0]);
    o[5] = (__bf16)((float)vb[5] + f1[1]);
    o[6] = (__bf16)((float)vb[6] + f1[2]);
    o[7] = (__bf16)((float)vb[7] + f1[3]);
    *(bf16x8*)&preLN16[(size_t)(m0 + row) * 1024 + n0 + c * 8] = o;
  }
}

// ---------------- K4: LayerNorm (bf16 input, 1 wave/row, 4 rows/block) -----
__global__ __launch_bounds__(256) void layernorm(const u16* __restrict__ x16,
                                                 const float* __restrict__ gamma,
                                                 const float* __restrict__ beta,
                                                 float* __restrict__ out) {
  int t = threadIdx.x;
  int w = t >> 6, l = t & 63;
  int row = blockIdx.x * 4 + w;
  const u16* xr = x16 + (size_t)row * 1024;
  float xv[16];
  float s = 0.f, s2 = 0.f;
#pragma unroll
  for (int c = 0; c < 2; ++c) {
    bf16x8 v = g8(xr + c * 512 + l * 8);
#pragma unroll
    for (int j = 0; j < 8; ++j) {
      float f = (float)v[j];
      xv[c * 8 + j] = f;
      s += f;
      s2 += f * f;
    }
  }
#pragma unroll
  for (int m = 1; m < 64; m <<= 1) {
    s += __shfl_xor(s, m);
    s2 += __shfl_xor(s2, m);
  }
  float mu = s * (1.0f / 1024.0f);
  float var = s2 * (1.0f / 1024.0f) - mu * mu;
  float rs = rsqrtf(var + 1e-5f);
  float* orow = out + (size_t)row * 1024;
#pragma unroll
  for (int c = 0; c < 2; ++c) {
#pragma unroll
    for (int q = 0; q < 2; ++q) {
      int off = c * 512 + l * 8 + q * 4;
      f32x4 g = *(const f32x4*)(gamma + off);
      f32x4 bb = *(const f32x4*)(beta + off);
      f32x4 o;
#pragma unroll
      for (int j = 0; j < 4; ++j)
        o[j] = (xv[c * 8 + q * 4 + j] - mu) * rs * g[j] + bb[j];
      *(f32x4*)(orow + off) = o;
    }
  }
}

// ---------------- launch ----------------
extern "C" void kernel_launch(void* const* d_in, const int* in_sizes, int n_in,
                              void* d_out, int out_size, void* d_ws, size_t ws_size,
                              hipStream_t stream) {
  const float* Xq = (const float*)d_in[0];
  const float* Xk = (const float*)d_in[1];
  const float* Xv = (const float*)d_in[2];
  const int* Mask = (const int*)d_in[3];
  const float* Wq = (const float*)d_in[4];
  const float* bq = (const float*)d_in[5];
  const float* Wk = (const float*)d_in[6];
  const float* bk = (const float*)d_in[7];
  const float* Wv = (const float*)d_in[8];
  const float* bv = (const float*)d_in[9];
  const float* Wo = (const float*)d_in[10];
  const float* bo = (const float*)d_in[11];
  const float* gamma = (const float*)d_in[12];
  const float* beta = (const float*)d_in[13];

  char* ws = (char*)d_ws;
  u16* Xbf   = (u16*)(ws + 0);            // 48 MiB (dead after gemm_qkv)
  u16* Wt    = (u16*)(ws + 50331648);     // 8 MiB
  u16* Qs    = (u16*)(ws + 58720256);     // 16 MiB (Q), then K contiguous
  u16* Vt    = (u16*)(ws + 92274688);     // 16 MiB [bh][dv][s]
  u32* Mbits = (u32*)(ws + 109051904);    // 2 MiB
  u16* Ctx   = (u16*)(ws + 111149056);    // 16 MiB
  u16* preLN16 = (u16*)(ws + 0);          // 16 MiB, aliases Xbf (dead by then)

  u16* Ks = Qs + 8192ull * 1024;

  float* outp = (float*)d_out;
  float* attn = outp + 8388608ull;

  (void)in_sizes; (void)n_in; (void)out_size; (void)ws_size;

  prep<<<46080, 256, 0, stream>>>(Xq, Xk, Xv, Wq, Wk, Wv, Wo, Mask, Xbf, Wt, Mbits);
  gemm_qkv<<<dim3(512, 1, 3), 256, 0, stream>>>(Xbf, Wt, bq, bk, bv, Qs, Vt);
  attn_kernel<<<2048, 256, 0, stream>>>(Qs, Ks, Vt, Mbits, attn, Ctx);
  gemm_out<<<512, 256, 0, stream>>>(Ctx, Wt + 3ull * 1048576, bo, Xq, preLN16);
  layernorm<<<2048, 256, 0, stream>>>(preLN16, gamma, beta, outp);
}